// Round 6
// baseline (463.853 us; speedup 1.0000x reference)
//
#include <hip/hip_runtime.h>
#include <hip/hip_bf16.h>

// UnifiedMambaBlock: B=2, L=1024, D_MODEL=2048, D_INNER=4096, N_STATE=16,
// DT_RANK=128, D_CONV=4.  ALL inputs/outputs fp32 (per reference dtypes).
// bf16 MFMA compute (no fp32 MFMA on CDNA4); fp32 epilogues.
//
// R13: scan back to 16 lanes/channel (R3-verified scalar math + 4-level DPP)
// with the R12 dt-fusion kept.  16 ch/block -> 512 blocks, LDS ~65.5 KB ->
// 2 blocks/CU = 2 waves/SIMD (R12 had 1 wave/SIMD, VALUBusy 37%: latency
// fully exposed).  dt tile per chunk = [128 t x 16 d] via MFMA.
// R12: dt GEMM fused into scan (no dtb HBM round-trip).
// R10: z-gate silu(z) precomputed in conv kernel; conv vectorized.
// R8: in_proj GEMM = 256x256 deep-pipelined schedule.

#define DEV __device__ __forceinline__

typedef __attribute__((ext_vector_type(8))) __bf16 bf16x8;
typedef __attribute__((ext_vector_type(4))) float f32x4;
typedef unsigned int u32;

DEV float bf2f(__hip_bfloat16 x) { return __bfloat162float(x); }
DEV __hip_bfloat16 f2bf(float x) { return __float2bfloat16(x); }
DEV float bfu2f(unsigned short u) {
    union { u32 i; float f; } c; c.i = ((u32)u) << 16; return c.f;
}
DEV unsigned short f2bfu(float x) {
    __hip_bfloat16 h = __float2bfloat16(x);
    return *reinterpret_cast<unsigned short*>(&h);
}
DEV float softplusf(float v) { return v > 20.f ? v : log1pf(__expf(v)); }
DEV float siluf(float v) { return v / (1.f + __expf(-v)); }
// fast softplus: ln(1+e^v) via v_exp_f32/v_log_f32 (log2-based).
DEV float softplus_fast(float v) {
    if (v > 20.f) return v;
    const float e = __builtin_amdgcn_exp2f(v * 1.44269504f);
    return 0.69314718f * __builtin_amdgcn_logf(1.f + e);
}

DEV void storeOut(float* C, size_t off, float v) { C[off] = v; }
DEV void storeOut(__hip_bfloat16* C, size_t off, float v) { C[off] = f2bf(v); }

// async 16B global -> LDS (global_load_lds_dwordx4).
// LDS destination must be wave-uniform base + lane*16 (HW constraint).
DEV void async16(void* lds, const void* g) {
    __builtin_amdgcn_global_load_lds(
        (const __attribute__((address_space(1))) u32*)(unsigned long long)g,
        (__attribute__((address_space(3))) u32*)(u32)(unsigned long long)lds,
        16, 0, 0);
}

// DPP-based add of lane (permuted) value; reduction over 16-lane rows.
// MUST stay as the builtin: compiler inserts required DPP hazard nops.
template <int CTRL>
DEV float dppadd(float v) {
    int x = __builtin_amdgcn_update_dpp(
        0, __builtin_bit_cast(int, v), CTRL, 0xF, 0xF, true);
    return v + __builtin_bit_cast(float, x);
}

// ---------------------------------------------------------------------------
// 256x256-tile deep-pipelined GEMM: C = A @ W^T + bias (bf16 in, bf16 out).
// 512 threads = 8 waves (2M x 4N), per-wave 128x64 output, BK=32.
// 4 LDS buffers, prefetch distance 3 tiles, counted vmcnt, T2 swizzle, T5.
// ---------------------------------------------------------------------------
__global__ __launch_bounds__(512, 2) void gemm256_bt(
    const __hip_bfloat16* __restrict__ A, int lda,
    const __hip_bfloat16* __restrict__ W, int ldw,
    const float* __restrict__ bias,
    __hip_bfloat16* __restrict__ C, int ldc, int K)
{
    __shared__ __align__(16) unsigned short As[4][256 * 32];  // 64 KB
    __shared__ __align__(16) unsigned short Bs[4][256 * 32];  // 64 KB

    const int t    = threadIdx.x;
    // T1: bijective XCD swizzle (nwg % 8 == 0 guaranteed by launch shapes)
    const int nwg  = gridDim.x * gridDim.y;
    const int orig = blockIdx.y * gridDim.x + blockIdx.x;
    const int swz  = (orig & 7) * (nwg >> 3) + (orig >> 3);
    const int mBase = (swz / gridDim.x) * 256;
    const int nBase = (swz % gridDim.x) * 256;

    const int wave = t >> 6;
    const int lane = t & 63;
    const int wm   = (wave >> 2) * 128;   // 2 M wave-groups
    const int wn   = (wave & 3) * 64;     // 4 N wave-groups
    const int ln15 = lane & 15;
    const int quad = lane >> 4;
    const int kof  = quad * 8;

    f32x4 acc[8][4];
    const f32x4 vzero = {0.f, 0.f, 0.f, 0.f};
#pragma unroll
    for (int i = 0; i < 8; ++i)
#pragma unroll
        for (int j = 0; j < 4; ++j) acc[i][j] = vzero;

    auto stage = [&](int buf, int k0, int half) {
        const int idx = half * 512 + t;                 // 0..1023 -> 16B slot
        const int le  = (idx * 8) ^ (((idx >> 3) & 3) << 3);
        const int r   = le >> 5;
        const int c   = le & 31;
        async16(&As[buf][idx * 8], A + (size_t)(mBase + r) * lda + k0 + c);
        async16(&Bs[buf][idx * 8], W + (size_t)(nBase + r) * ldw + k0 + c);
    };

    const int NT = K >> 5;

#pragma unroll 1
    for (int p = 0; p < 3 && p < NT; ++p) {
        stage(p, p << 5, 0);
        stage(p, p << 5, 1);
    }

#pragma unroll 1
    for (int T = 0; T < NT; ++T) {
        const int buf = T & 3;
        if (T + 2 < NT)      asm volatile("s_waitcnt vmcnt(8)" ::: "memory");
        else if (T + 1 < NT) asm volatile("s_waitcnt vmcnt(4)" ::: "memory");
        else                 asm volatile("s_waitcnt vmcnt(0)" ::: "memory");
        __builtin_amdgcn_s_barrier();          // all waves' vmcnt passed
        __builtin_amdgcn_sched_barrier(0);     // no ds_read hoists above

        const unsigned short* __restrict__ Ab = As[buf];
        const unsigned short* __restrict__ Bb = Bs[buf];
        const int k0n  = (T + 3) << 5;
        const int bufn = (T + 3) & 3;          // != buf; == (T-1)&3 (dead)

        // ---- phase 1: A-frags 0-3 + all B-frags, 16 MFMA ----
        bf16x8 af[4], bfr[4], af2[4];
#pragma unroll
        for (int i = 0; i < 4; ++i) {
            const int ra = wm + i * 16 + ln15;
            af[i] = *reinterpret_cast<const bf16x8*>(
                &Ab[(ra * 32 + kof) ^ (((ra >> 1) & 3) << 3)]);
            const int rb = wn + i * 16 + ln15;
            bfr[i] = *reinterpret_cast<const bf16x8*>(
                &Bb[(rb * 32 + kof) ^ (((rb >> 1) & 3) << 3)]);
        }
        if (T + 3 < NT) stage(bufn, k0n, 0);
        __builtin_amdgcn_s_barrier();
        __builtin_amdgcn_s_setprio(1);
#pragma unroll
        for (int i = 0; i < 4; ++i)
#pragma unroll
            for (int j = 0; j < 4; ++j)
                acc[i][j] = __builtin_amdgcn_mfma_f32_16x16x32_bf16(
                    af[i], bfr[j], acc[i][j], 0, 0, 0);
        __builtin_amdgcn_s_setprio(0);
        __builtin_amdgcn_sched_barrier(0);

        // ---- phase 2: A-frags 4-7 (reuse B-frags), 16 MFMA ----
#pragma unroll
        for (int i = 0; i < 4; ++i) {
            const int ra = wm + 64 + i * 16 + ln15;
            af2[i] = *reinterpret_cast<const bf16x8*>(
                &Ab[(ra * 32 + kof) ^ (((ra >> 1) & 3) << 3)]);
        }
        if (T + 3 < NT) stage(bufn, k0n, 1);
        __builtin_amdgcn_s_barrier();
        __builtin_amdgcn_s_setprio(1);
#pragma unroll
        for (int i = 0; i < 4; ++i)
#pragma unroll
            for (int j = 0; j < 4; ++j)
                acc[4 + i][j] = __builtin_amdgcn_mfma_f32_16x16x32_bf16(
                    af2[i], bfr[j], acc[4 + i][j], 0, 0, 0);
        __builtin_amdgcn_s_setprio(0);
        __builtin_amdgcn_sched_barrier(0);
    }

    // epilogue: C/D layout col = lane&15, row = quad*4 + reg
#pragma unroll
    for (int i = 0; i < 8; ++i) {
        const int gm = mBase + wm + i * 16 + quad * 4;
#pragma unroll
        for (int j = 0; j < 4; ++j) {
            const int gn = nBase + wn + j * 16 + ln15;
            const float bv = bias ? bias[gn] : 0.f;
#pragma unroll
            for (int r = 0; r < 4; ++r)
                C[(size_t)(gm + r) * ldc + gn] = f2bf(acc[i][j][r] + bv);
        }
    }
}

// ---------------------------------------------------------------------------
// C = A @ W^T + bias GEMM, bf16 inputs, DOUBLE-BUFFERED async LDS staging.
// Block tile 128x128, BK=64, 256 threads = 4 waves 2x2, wave does 64x64.
// ---------------------------------------------------------------------------
template <int ACT, typename OutT>
__global__ __launch_bounds__(256) void gemm_bt(
    const __hip_bfloat16* __restrict__ A, int lda,
    const __hip_bfloat16* __restrict__ W, int ldw,
    const float* __restrict__ bias,
    OutT* __restrict__ C, int ldc, int K)
{
    __shared__ __align__(16) unsigned short AsU[2][128 * 64];
    __shared__ __align__(16) unsigned short BsU[2][128 * 64];

    const int t     = threadIdx.x;
    const int mBase = blockIdx.y * 128;
    const int nBase = blockIdx.x * 128;
    const int wave  = t >> 6;
    const int lane  = t & 63;
    const int wm    = (wave >> 1) * 64;
    const int wn    = (wave & 1) * 64;
    const int ln15  = lane & 15;
    const int quad  = lane >> 4;

    f32x4 acc[4][4];
    const f32x4 vzero = {0.f, 0.f, 0.f, 0.f};
#pragma unroll
    for (int i = 0; i < 4; ++i)
#pragma unroll
        for (int j = 0; j < 4; ++j) acc[i][j] = vzero;

    auto stage = [&](int buf, int k0) {
#pragma unroll
        for (int i = 0; i < 4; ++i) {
            int idx = i * 256 + t;
            int r = idx >> 3;
            int c = (idx & 7) << 3;
            async16(&AsU[buf][idx * 8], A + (size_t)(mBase + r) * lda + k0 + c);
            async16(&BsU[buf][idx * 8], W + (size_t)(nBase + r) * ldw + k0 + c);
        }
    };

    const int nIter = K >> 6;
    stage(0, 0);

    for (int it = 0; it < nIter; ++it) {
        __syncthreads();   // buf[it&1] resident; prior reads of other buf done
        if (it + 1 < nIter) stage((it + 1) & 1, (it + 1) << 6);
        const unsigned short* As = AsU[it & 1];
        const unsigned short* Bs = BsU[it & 1];

#pragma unroll
        for (int kk = 0; kk < 64; kk += 32) {
            const int kof = kk + quad * 8;
            bf16x8 af[4], bfr[4];
#pragma unroll
            for (int i = 0; i < 4; ++i) {
                af[i]  = *reinterpret_cast<const bf16x8*>(&As[(wm + i * 16 + ln15) * 64 + kof]);
                bfr[i] = *reinterpret_cast<const bf16x8*>(&Bs[(wn + i * 16 + ln15) * 64 + kof]);
            }
#pragma unroll
            for (int i = 0; i < 4; ++i)
#pragma unroll
                for (int j = 0; j < 4; ++j)
                    acc[i][j] = __builtin_amdgcn_mfma_f32_16x16x32_bf16(af[i], bfr[j], acc[i][j], 0, 0, 0);
        }
    }

    // epilogue: C/D layout col = lane&15, row = quad*4 + reg
#pragma unroll
    for (int i = 0; i < 4; ++i) {
        const int gm = mBase + wm + i * 16 + quad * 4;
#pragma unroll
        for (int j = 0; j < 4; ++j) {
            const int gn = nBase + wn + j * 16 + ln15;
            const float bv = bias ? bias[gn] : 0.f;
#pragma unroll
            for (int r = 0; r < 4; ++r) {
                float v = acc[i][j][r] + bv;
                if (ACT == 1) v = softplusf(v);
                storeOut(C, (size_t)(gm + r) * ldc + gn, v);
            }
        }
    }
}

// ---------------------------------------------------------------------------
// Split-K variant: grid (nx, ny, SLICES); slice z handles K-range
// [z*K/SLICES, (z+1)*K/SLICES), stores fp32 partial at part + z*sliceElems.
// ---------------------------------------------------------------------------
__global__ __launch_bounds__(256) void gemm_bt_sk(
    const __hip_bfloat16* __restrict__ A, int lda,
    const __hip_bfloat16* __restrict__ W, int ldw,
    float* __restrict__ part, int ldc, int K, int slices, int sliceElems)
{
    __shared__ __align__(16) unsigned short AsU[2][128 * 64];
    __shared__ __align__(16) unsigned short BsU[2][128 * 64];

    const int t     = threadIdx.x;
    const int mBase = blockIdx.y * 128;
    const int nBase = blockIdx.x * 128;
    const int kLen  = K / slices;
    const int kOff  = blockIdx.z * kLen;
    const int wave  = t >> 6;
    const int lane  = t & 63;
    const int wm    = (wave >> 1) * 64;
    const int wn    = (wave & 1) * 64;
    const int ln15  = lane & 15;
    const int quad  = lane >> 4;

    f32x4 acc[4][4];
    const f32x4 vzero = {0.f, 0.f, 0.f, 0.f};
#pragma unroll
    for (int i = 0; i < 4; ++i)
#pragma unroll
        for (int j = 0; j < 4; ++j) acc[i][j] = vzero;

    auto stage = [&](int buf, int k0) {
#pragma unroll
        for (int i = 0; i < 4; ++i) {
            int idx = i * 256 + t;
            int r = idx >> 3;
            int c = (idx & 7) << 3;
            async16(&AsU[buf][idx * 8], A + (size_t)(mBase + r) * lda + k0 + c);
            async16(&BsU[buf][idx * 8], W + (size_t)(nBase + r) * ldw + k0 + c);
        }
    };

    const int nIter = kLen >> 6;
    stage(0, kOff);

    for (int it = 0; it < nIter; ++it) {
        __syncthreads();
        if (it + 1 < nIter) stage((it + 1) & 1, kOff + ((it + 1) << 6));
        const unsigned short* As = AsU[it & 1];
        const unsigned short* Bs = BsU[it & 1];

#pragma unroll
        for (int kk = 0; kk < 64; kk += 32) {
            const int kof = kk + quad * 8;
            bf16x8 af[4], bfr[4];
#pragma unroll
            for (int i = 0; i < 4; ++i) {
                af[i]  = *reinterpret_cast<const bf16x8*>(&As[(wm + i * 16 + ln15) * 64 + kof]);
                bfr[i] = *reinterpret_cast<const bf16x8*>(&Bs[(wn + i * 16 + ln15) * 64 + kof]);
            }
#pragma unroll
            for (int i = 0; i < 4; ++i)
#pragma unroll
                for (int j = 0; j < 4; ++j)
                    acc[i][j] = __builtin_amdgcn_mfma_f32_16x16x32_bf16(af[i], bfr[j], acc[i][j], 0, 0, 0);
        }
    }

    float* Cp = part + (size_t)blockIdx.z * sliceElems;
#pragma unroll
    for (int i = 0; i < 4; ++i) {
        const int gm = mBase + wm + i * 16 + quad * 4;
#pragma unroll
        for (int j = 0; j < 4; ++j) {
            const int gn = nBase + wn + j * 16 + ln15;
#pragma unroll
            for (int r = 0; r < 4; ++r)
                Cp[(size_t)(gm + r) * ldc + gn] = acc[i][j][r];
        }
    }
}

// sum 8 fp32 partials -> bf16 proj.  total = 2048*256 elems.
__global__ __launch_bounds__(256) void reduce_proj(
    const float* __restrict__ part, __hip_bfloat16* __restrict__ proj)
{
    int i = blockIdx.x * 256 + threadIdx.x;
    float s = 0.f;
#pragma unroll
    for (int z = 0; z < 8; ++z) s += part[(size_t)z * 524288 + i];
    proj[i] = f2bf(s);
}

// ---------------------------------------------------------------------------
// fp32 -> bf16 cast, 8 elems/thread.  n must be a multiple of 2048.
// ---------------------------------------------------------------------------
__global__ __launch_bounds__(256) void cast_f32_bf16(
    const float* __restrict__ in, __hip_bfloat16* __restrict__ out)
{
    size_t i = ((size_t)blockIdx.x * 256 + threadIdx.x) * 8;
    const float4 a = *reinterpret_cast<const float4*>(in + i);
    const float4 b = *reinterpret_cast<const float4*>(in + i + 4);
    unsigned short r[8];
    r[0] = f2bfu(a.x); r[1] = f2bfu(a.y); r[2] = f2bfu(a.z); r[3] = f2bfu(a.w);
    r[4] = f2bfu(b.x); r[5] = f2bfu(b.y); r[6] = f2bfu(b.z); r[7] = f2bfu(b.w);
    *reinterpret_cast<uint4*>(out + i) = *reinterpret_cast<uint4*>(r);
}

// ---------------------------------------------------------------------------
// wcat bf16 [256,4096]: rows 0..127 w_xdt, 128..143 w_xb, 144..159 w_xc.
// ---------------------------------------------------------------------------
__global__ __launch_bounds__(256) void build_wcat(
    const float* __restrict__ w_xdt,
    const float* __restrict__ w_xb,
    const float* __restrict__ w_xc,
    __hip_bfloat16* __restrict__ wcat)
{
    int tid = blockIdx.x * 256 + threadIdx.x;
    int r = tid >> 12;
    int c = tid & 4095;
    float v = 0.f;
    if (r < 128)      v = w_xdt[r * 4096 + c];
    else if (r < 144) v = w_xb[(r - 128) * 4096 + c];
    else if (r < 160) v = w_xc[(r - 144) * 4096 + c];
    wcat[tid] = f2bf(v);
}

// ---------------------------------------------------------------------------
// Vectorized causal depthwise conv (win 4, left pad 3) + bias + silu over
// xz[:, :4096] -> xc, AND silu over xz[:, 4096:] IN PLACE (z-gate precompute
// for the scan).  8 outputs per thread, uint4 loads/stores.
// ---------------------------------------------------------------------------
__global__ __launch_bounds__(256) void conv_siluz(
    const __hip_bfloat16* __restrict__ xzr,
    __hip_bfloat16* __restrict__ xzw,          // same buffer, z-half writes
    const float* __restrict__ conv_w,
    const float* __restrict__ conv_b,
    __hip_bfloat16* __restrict__ xc)
{
    const int tid = blockIdx.x * 256 + threadIdx.x;
    if (tid < (1 << 20)) {
        const int row = tid >> 9;            // 0..2047 (b*1024 + l)
        const int d8  = (tid & 511) << 3;    // 0..4088 step 8
        const int l   = row & 1023;
        uint4 tv[4];
#pragma unroll
        for (int k = 0; k < 4; ++k) {
            const int ll = l - 3 + k;
            if (ll >= 0)
                tv[k] = *reinterpret_cast<const uint4*>(
                    &xzr[(size_t)(row - 3 + k) * 8192 + d8]);
            else
                tv[k] = make_uint4(0u, 0u, 0u, 0u);   // bf16 zeros
        }
        const float4 b0 = *reinterpret_cast<const float4*>(&conv_b[d8]);
        const float4 b1 = *reinterpret_cast<const float4*>(&conv_b[d8 + 4]);
        const unsigned short* t0 = (const unsigned short*)&tv[0];
        const unsigned short* t1 = (const unsigned short*)&tv[1];
        const unsigned short* t2 = (const unsigned short*)&tv[2];
        const unsigned short* t3 = (const unsigned short*)&tv[3];
        unsigned short o[8];
#pragma unroll
        for (int j = 0; j < 8; ++j) {
            const float4 w = *reinterpret_cast<const float4*>(&conv_w[(d8 + j) * 4]);
            float acc = (j < 4) ? ((const float*)&b0)[j] : ((const float*)&b1)[j - 4];
            acc += bfu2f(t0[j]) * w.x;
            acc += bfu2f(t1[j]) * w.y;
            acc += bfu2f(t2[j]) * w.z;
            acc += bfu2f(t3[j]) * w.w;
            o[j] = f2bfu(siluf(acc));
        }
        *reinterpret_cast<uint4*>(&xc[(size_t)row * 4096 + d8]) =
            *reinterpret_cast<const uint4*>(o);
    } else {
        const int zi  = tid - (1 << 20);
        const int row = zi >> 9;
        const int d8  = (zi & 511) << 3;
        const size_t a = (size_t)row * 8192 + 4096 + d8;
        const uint4 v = *reinterpret_cast<const uint4*>(&xzr[a]);
        const unsigned short* zv = (const unsigned short*)&v;
        unsigned short o[8];
#pragma unroll
        for (int j = 0; j < 8; ++j)
            o[j] = f2bfu(siluf(bfu2f(zv[j])));
        *reinterpret_cast<uint4*>(&xzw[a]) = *reinterpret_cast<const uint4*>(o);
    }
}

// ---------------------------------------------------------------------------
// selective scan with FUSED dt computation, 16 lanes/channel.
// 16 channels/block, 512 blocks, 256 threads.  LDS ~65.5 KB -> 2 blocks/CU
// (2 waves/SIMD).  Per chunk (128 t): stage proj[:, :128] chunk into s_pa
// (XOR-swizzled via pre-swizzled async16 source), MFMA [128t x 16d] dt-tile
// against s_wd (w_dt rows), softplus -> s_dt[d][t]; then the scan.
// z-half of xz holds PRE-GATED silu(z).
// ---------------------------------------------------------------------------
#define SCAN_T 128
#define ST4 132
#define ST2 136

__global__ __launch_bounds__(256) void scan_kernel(
    const __hip_bfloat16* __restrict__ proj,   // [2048,256]; dt-K at 0, B at 128, C at 144
    __hip_bfloat16* xcyg,                      // [2048, 4096] bf16 in/out
    const __hip_bfloat16* __restrict__ xz,     // [2048, 8192]; zg at 4096+d
    const __hip_bfloat16* __restrict__ wdt,    // [4096, 128] bf16
    const float* __restrict__ bdt,             // [4096] fp32
    const float* __restrict__ A_log,           // [4096, 16] fp32
    const float* __restrict__ Dp)              // [4096] fp32
{
    __shared__ __align__(16) float          s_dt[16 * ST4];   // [d][time]
    __shared__ __align__(16) unsigned short s_x [16 * ST2];
    __shared__ __align__(16) unsigned short s_z [16 * ST2];
    __shared__ __align__(16) unsigned short s_B [16 * ST2];   // [state][time]
    __shared__ __align__(16) unsigned short s_C [16 * ST2];
    __shared__ __align__(16) unsigned short s_y [16 * ST2];
    __shared__ __align__(16) unsigned short s_pa[128 * 128];  // proj chunk [t][k], swz
    __shared__ __align__(16) unsigned short s_wd[16 * 128];   // w_dt [d][k], swz

    const int t    = threadIdx.x;
    const int g    = t >> 4;         // channel in block, 0..15
    const int n    = t & 15;         // state
    const int wave = t >> 6;
    const int lane = t & 63;
    const int ln15 = lane & 15;
    const int quad = lane >> 4;
    const int wm32 = wave * 32;      // wave's 32-row t-stripe of the dt tile
    const int ch0  = blockIdx.x * 16;
    const int b    = ch0 >> 12;
    const int d0   = ch0 & 4095;
    const int d    = d0 + g;

    const float A2   = -__expf(A_log[d * 16 + n]) * 1.44269504f;
    const float Dpar = Dp[d];
    const size_t rowBase = (size_t)b * 1024;
    const float bdtv = bdt[d0 + ln15];   // lane's d-column of the dt tile

    // stage w_dt rows d0..d0+15 once (XOR-swizzled source, linear LDS dest)
    {
        const int idx = t;               // 256 slots of 16B = 16 rows x 128
        const int le  = (idx * 8) ^ (((idx >> 4) & 7) << 3);
        async16(&s_wd[idx * 8], &wdt[(size_t)(d0 + (idx >> 4)) * 128 + (le & 127)]);
    }

    // staging thread mappings (128 time-rows per chunk)
    const int lrow = t >> 1;             // 0..127
    const int lh8  = (t & 1) << 3;       // 0 or 8

    uint4 rx, rz, rBv, rCv;
    auto load_chunk = [&](int t0) {
        rx  = *reinterpret_cast<const uint4*>(
            &xcyg[(rowBase + t0 + lrow) * 4096 + d0 + lh8]);
        rz  = *reinterpret_cast<const uint4*>(
            &xz[(rowBase + t0 + lrow) * 8192 + 4096 + d0 + lh8]);
        rBv = *reinterpret_cast<const uint4*>(
            &proj[(rowBase + t0 + lrow) * 256 + 128 + lh8]);
        rCv = *reinterpret_cast<const uint4*>(
            &proj[(rowBase + t0 + lrow) * 256 + 144 + lh8]);
    };

    load_chunk(0);
    float h = 0.f;

#pragma unroll 1
    for (int c = 0; c < 1024 / SCAN_T; ++c) {
        const int t0 = c * SCAN_T;
        __syncthreads();                 // prior chunk's LDS reads complete

        // stage proj chunk rows t0..t0+127, cols 0..127 (async -> s_pa)
#pragma unroll
        for (int s = 0; s < 8; ++s) {
            const int idx = s * 256 + t;
            const int le  = (idx * 8) ^ (((idx >> 4) & 7) << 3);
            async16(&s_pa[idx * 8],
                    &proj[(rowBase + t0 + (idx >> 4)) * 256 + (le & 127)]);
        }
        // write prefetched x/z/B/C regs into LDS (transposed)
        {
            const unsigned short* px = (const unsigned short*)&rx;
            const unsigned short* pz = (const unsigned short*)&rz;
            const unsigned short* pB = (const unsigned short*)&rBv;
            const unsigned short* pC = (const unsigned short*)&rCv;
#pragma unroll
            for (int jj = 0; jj < 8; ++jj) {
                s_x[(lh8 + jj) * ST2 + lrow] = px[jj];
                s_z[(lh8 + jj) * ST2 + lrow] = pz[jj];
                s_B[(lh8 + jj) * ST2 + lrow] = pB[jj];
                s_C[(lh8 + jj) * ST2 + lrow] = pC[jj];
            }
        }
        __syncthreads();                 // drains vmcnt: s_pa/s_wd resident
        if (c + 1 < 1024 / SCAN_T) load_chunk(t0 + SCAN_T);

        // ---- fused dt tile: [128 t x 16 d] = softplus(projK @ wdt^T + bdt)
        {
            f32x4 dacc[2];
            const f32x4 vz4 = {0.f, 0.f, 0.f, 0.f};
            dacc[0] = vz4; dacc[1] = vz4;
#pragma unroll
            for (int ks = 0; ks < 4; ++ks) {
                const int kof = ks * 32 + quad * 8;
                bf16x8 paf[2], wbf;
#pragma unroll
                for (int i = 0; i < 2; ++i) {
                    const int ra = wm32 + i * 16 + ln15;
                    paf[i] = *reinterpret_cast<const bf16x8*>(
                        &s_pa[(ra * 128 + kof) ^ ((ra & 7) << 3)]);
                }
                {
                    const int rb = ln15;
                    wbf = *reinterpret_cast<const bf16x8*>(
                        &s_wd[(rb * 128 + kof) ^ ((rb & 7) << 3)]);
                }
#pragma unroll
                for (int i = 0; i < 2; ++i)
                    dacc[i] = __builtin_amdgcn_mfma_f32_16x16x32_bf16(
                        paf[i], wbf, dacc[i], 0, 0, 0);
            }
            // epilogue: C[m=t, n=d]; col=ln15, row=quad*4+r -> s_dt[d][t]
#pragma unroll
            for (int i = 0; i < 2; ++i) {
                const int tb = wm32 + i * 16 + quad * 4;
                const int dd = ln15;
                f32x4 w;
#pragma unroll
                for (int r = 0; r < 4; ++r)
                    w[r] = softplus_fast(dacc[i][r] + bdtv);
                *reinterpret_cast<f32x4*>(&s_dt[dd * ST4 + tb]) = w;
            }
        }
        __syncthreads();                 // s_dt visible to all waves

#pragma unroll 1
        for (int l0 = 0; l0 < SCAN_T; l0 += 8) {
            const uint4 vx = *reinterpret_cast<const uint4*>(&s_x[g * ST2 + l0]);
            const uint4 vz = *reinterpret_cast<const uint4*>(&s_z[g * ST2 + l0]);
            const uint4 vB = *reinterpret_cast<const uint4*>(&s_B[n * ST2 + l0]);
            const uint4 vC = *reinterpret_cast<const uint4*>(&s_C[n * ST2 + l0]);
            const float4 vd0 = *reinterpret_cast<const float4*>(&s_dt[g * ST4 + l0]);
            const float4 vd1 = *reinterpret_cast<const float4*>(&s_dt[g * ST4 + l0 + 4]);
            const unsigned short* ux = (const unsigned short*)&vx;
            const unsigned short* uz = (const unsigned short*)&vz;
            const unsigned short* uB = (const unsigned short*)&vB;
            const unsigned short* uC = (const unsigned short*)&vC;
            const float* fd0 = (const float*)&vd0;
            const float* fd1 = (const float*)&vd1;
            unsigned short y8[8];
#pragma unroll
            for (int j = 0; j < 8; ++j) {
                const float dtv = (j < 4) ? fd0[j] : fd1[j - 4];
                const float xv  = bfu2f(ux[j]);
                const float Bn  = bfu2f(uB[j]);
                const float Cn  = bfu2f(uC[j]);
                const float e   = __builtin_amdgcn_exp2f(dtv * A2);
                h = fmaf(h, e, (xv * dtv) * Bn);
                float p = h * Cn;
                p = dppadd<0xB1>(p);
                p = dppadd<0x4E>(p);
                p = dppadd<0x141>(p);
                p = dppadd<0x140>(p);
                if (n == 0) {
                    const float zgv = bfu2f(uz[j]);   // pre-gated silu(z)
                    y8[j] = f2bfu((p + Dpar * xv) * zgv);
                }
            }
            if (n == 0)
                *reinterpret_cast<uint4*>(&s_y[g * ST2 + l0]) =
                    *reinterpret_cast<const uint4*>(y8);
        }
        __syncthreads();

        {
            unsigned short tmp[8];
#pragma unroll
            for (int jj = 0; jj < 8; ++jj) tmp[jj] = s_y[(lh8 + jj) * ST2 + lrow];
            *reinterpret_cast<uint4*>(
                &xcyg[(rowBase + t0 + lrow) * 4096 + d0 + lh8]) =
                *reinterpret_cast<const uint4*>(tmp);
        }
    }
}

// ---------------------------------------------------------------------------
extern "C" void kernel_launch(void* const* d_in, const int* in_sizes, int n_in,
                              void* d_out, int out_size, void* d_ws, size_t ws_size,
                              hipStream_t stream)
{
    const float* u      = (const float*)d_in[0];
    const float* w_in   = (const float*)d_in[1];
    const float* b_in   = (const float*)d_in[2];
    const float* w_out  = (const float*)d_in[3];
    const float* b_out  = (const float*)d_in[4];
    const float* w_dt   = (const float*)d_in[5];
    const float* b_dt   = (const float*)d_in[6];
    const float* w_xdt  = (const float*)d_in[7];
    const float* w_xb   = (const float*)d_in[8];
    const float* w_xc   = (const float*)d_in[9];
    const float* conv_w = (const float*)d_in[10];
    const float* conv_b = (const float*)d_in[11];
    const float* A_log  = (const float*)d_in[12];
    const float* D_par  = (const float*)d_in[13];
    float* out = (float*)d_out;

    char* ws = (char*)d_ws;
    __hip_bfloat16* xz    = (__hip_bfloat16*)(ws);             // [2048,8192] 33.5 MB
    __hip_bfloat16* xc    = (__hip_bfloat16*)(ws + 33554432);  // [2048,4096] 16.8 MB
    __hip_bfloat16* u_bf  = (__hip_bfloat16*)(ws + 33554432);  // dead before xc written
    __hip_bfloat16* wcat  = (__hip_bfloat16*)(ws + 50331648);  // [256,4096]  2.1 MB
    __hip_bfloat16* w_dt_bf = (__hip_bfloat16*)(ws + 50331648);// [4096,128] 1 MB (after wcat dead)
    __hip_bfloat16* proj  = (__hip_bfloat16*)(ws + 52428800);  // [2048,256]  1.0 MB
    __hip_bfloat16* w_in_bf  = (__hip_bfloat16*)(ws + 53477376); // [8192,2048] bf16 33.5MB
    float*          projPart = (float*)(ws + 53477376);         // [8,2048,256] 16.8 MB (after w_in_bf dead)
    __hip_bfloat16* w_out_bf = (__hip_bfloat16*)(ws + 53477376); // after scan
    // total 87.0 MB

    // 0. pre-cast to bf16
    cast_f32_bf16<<<2048, 256, 0, stream>>>(u, u_bf);
    cast_f32_bf16<<<8192, 256, 0, stream>>>(w_in, w_in_bf);

    // 1. weight concat
    build_wcat<<<4096, 256, 0, stream>>>(w_xdt, w_xb, w_xc, wcat);

    // 2. in_proj: xz = u @ w_in^T + b_in   (M=2048, N=8192, K=2048)
    gemm256_bt<<<dim3(32, 8), 512, 0, stream>>>(
        u_bf, 2048, w_in_bf, 2048, b_in, xz, 8192, 2048);

    // 3. conv + silu -> xc; silu(z) in place over xz z-half (z-gate)
    conv_siluz<<<8192, 256, 0, stream>>>(xz, xz, conv_w, conv_b, xc);

    // 4. proj = xc @ wcat^T, split-K=8      (M=2048, N=256, K=4096)
    gemm_bt_sk<<<dim3(2, 16, 8), 256, 0, stream>>>(
        xc, 4096, wcat, 4096, projPart, 256, 4096, 8, 524288);
    reduce_proj<<<2048, 256, 0, stream>>>(projPart, proj);

    // 5. cast w_dt (wcat region dead now)
    cast_f32_bf16<<<256, 256, 0, stream>>>(w_dt, w_dt_bf);

    // 6+7. selective scan with FUSED dt GEMM -> yg (in-place over xc)
    scan_kernel<<<512, 256, 0, stream>>>(
        proj, xc, xz, w_dt_bf, b_dt, A_log, D_par);

    // 8. cast w_out (projPart region dead now)
    cast_f32_bf16<<<4096, 256, 0, stream>>>(w_out, w_out_bf);

    // 9. out = yg @ w_out^T + b_out          (M=2048, N=2048, K=4096)
    gemm_bt<0, float><<<dim3(16, 16), 256, 0, stream>>>(
        xc, 4096, w_out_bf, 4096, b_out, out, 2048, 4096);
}

// Round 7
// 457.623 us; speedup vs baseline: 1.0136x; 1.0136x over previous
//
#include <hip/hip_runtime.h>
#include <hip/hip_bf16.h>

// UnifiedMambaBlock: B=2, L=1024, D_MODEL=2048, D_INNER=4096, N_STATE=16,
// DT_RANK=128, D_CONV=4.  ALL inputs/outputs fp32 (per reference dtypes).
// bf16 MFMA compute (no fp32 MFMA on CDNA4); fp32 epilogues.
//
// R14: launch-count diet -- the 4 independent prep kernels (cast u, cast
// w_in, build_wcat, cast w_dt) fused into ONE prep_all dispatch (block-range
// switch, bodies unchanged).  11 -> 8 launches.  Out-proj gemm_bt gains the
// T1 bijective XCD swizzle (grid 256 % 8 == 0).
// R13: scan = 16 lanes/channel, fused dt MFMA tile, 512 blocks, 2 blk/CU.
// R12: dt GEMM fused into scan (no dtb HBM round-trip).
// R10: z-gate silu(z) precomputed in conv kernel; conv vectorized.
// R8: in_proj GEMM = 256x256 deep-pipelined schedule.

#define DEV __device__ __forceinline__

typedef __attribute__((ext_vector_type(8))) __bf16 bf16x8;
typedef __attribute__((ext_vector_type(4))) float f32x4;
typedef unsigned int u32;

DEV float bf2f(__hip_bfloat16 x) { return __bfloat162float(x); }
DEV __hip_bfloat16 f2bf(float x) { return __float2bfloat16(x); }
DEV float bfu2f(unsigned short u) {
    union { u32 i; float f; } c; c.i = ((u32)u) << 16; return c.f;
}
DEV unsigned short f2bfu(float x) {
    __hip_bfloat16 h = __float2bfloat16(x);
    return *reinterpret_cast<unsigned short*>(&h);
}
DEV float softplusf(float v) { return v > 20.f ? v : log1pf(__expf(v)); }
DEV float siluf(float v) { return v / (1.f + __expf(-v)); }
// fast softplus: ln(1+e^v) via v_exp_f32/v_log_f32 (log2-based).
DEV float softplus_fast(float v) {
    if (v > 20.f) return v;
    const float e = __builtin_amdgcn_exp2f(v * 1.44269504f);
    return 0.69314718f * __builtin_amdgcn_logf(1.f + e);
}

DEV void storeOut(float* C, size_t off, float v) { C[off] = v; }
DEV void storeOut(__hip_bfloat16* C, size_t off, float v) { C[off] = f2bf(v); }

// async 16B global -> LDS (global_load_lds_dwordx4).
// LDS destination must be wave-uniform base + lane*16 (HW constraint).
DEV void async16(void* lds, const void* g) {
    __builtin_amdgcn_global_load_lds(
        (const __attribute__((address_space(1))) u32*)(unsigned long long)g,
        (__attribute__((address_space(3))) u32*)(u32)(unsigned long long)lds,
        16, 0, 0);
}

// DPP-based add of lane (permuted) value; reduction over 16-lane rows.
// MUST stay as the builtin: compiler inserts required DPP hazard nops.
template <int CTRL>
DEV float dppadd(float v) {
    int x = __builtin_amdgcn_update_dpp(
        0, __builtin_bit_cast(int, v), CTRL, 0xF, 0xF, true);
    return v + __builtin_bit_cast(float, x);
}

// vectorized 8-elem fp32->bf16 cast at element index i*8
DEV void cast8(const float* __restrict__ in, __hip_bfloat16* __restrict__ out,
               size_t i8) {
    const size_t i = i8 * 8;
    const float4 a = *reinterpret_cast<const float4*>(in + i);
    const float4 b = *reinterpret_cast<const float4*>(in + i + 4);
    unsigned short r[8];
    r[0] = f2bfu(a.x); r[1] = f2bfu(a.y); r[2] = f2bfu(a.z); r[3] = f2bfu(a.w);
    r[4] = f2bfu(b.x); r[5] = f2bfu(b.y); r[6] = f2bfu(b.z); r[7] = f2bfu(b.w);
    *reinterpret_cast<uint4*>(out + i) = *reinterpret_cast<uint4*>(r);
}

// ---------------------------------------------------------------------------
// 256x256-tile deep-pipelined GEMM: C = A @ W^T + bias (bf16 in, bf16 out).
// 512 threads = 8 waves (2M x 4N), per-wave 128x64 output, BK=32.
// 4 LDS buffers, prefetch distance 3 tiles, counted vmcnt, T2 swizzle, T5.
// ---------------------------------------------------------------------------
__global__ __launch_bounds__(512, 2) void gemm256_bt(
    const __hip_bfloat16* __restrict__ A, int lda,
    const __hip_bfloat16* __restrict__ W, int ldw,
    const float* __restrict__ bias,
    __hip_bfloat16* __restrict__ C, int ldc, int K)
{
    __shared__ __align__(16) unsigned short As[4][256 * 32];  // 64 KB
    __shared__ __align__(16) unsigned short Bs[4][256 * 32];  // 64 KB

    const int t    = threadIdx.x;
    // T1: bijective XCD swizzle (nwg % 8 == 0 guaranteed by launch shapes)
    const int nwg  = gridDim.x * gridDim.y;
    const int orig = blockIdx.y * gridDim.x + blockIdx.x;
    const int swz  = (orig & 7) * (nwg >> 3) + (orig >> 3);
    const int mBase = (swz / gridDim.x) * 256;
    const int nBase = (swz % gridDim.x) * 256;

    const int wave = t >> 6;
    const int lane = t & 63;
    const int wm   = (wave >> 2) * 128;   // 2 M wave-groups
    const int wn   = (wave & 3) * 64;     // 4 N wave-groups
    const int ln15 = lane & 15;
    const int quad = lane >> 4;
    const int kof  = quad * 8;

    f32x4 acc[8][4];
    const f32x4 vzero = {0.f, 0.f, 0.f, 0.f};
#pragma unroll
    for (int i = 0; i < 8; ++i)
#pragma unroll
        for (int j = 0; j < 4; ++j) acc[i][j] = vzero;

    auto stage = [&](int buf, int k0, int half) {
        const int idx = half * 512 + t;                 // 0..1023 -> 16B slot
        const int le  = (idx * 8) ^ (((idx >> 3) & 3) << 3);
        const int r   = le >> 5;
        const int c   = le & 31;
        async16(&As[buf][idx * 8], A + (size_t)(mBase + r) * lda + k0 + c);
        async16(&Bs[buf][idx * 8], W + (size_t)(nBase + r) * ldw + k0 + c);
    };

    const int NT = K >> 5;

#pragma unroll 1
    for (int p = 0; p < 3 && p < NT; ++p) {
        stage(p, p << 5, 0);
        stage(p, p << 5, 1);
    }

#pragma unroll 1
    for (int T = 0; T < NT; ++T) {
        const int buf = T & 3;
        if (T + 2 < NT)      asm volatile("s_waitcnt vmcnt(8)" ::: "memory");
        else if (T + 1 < NT) asm volatile("s_waitcnt vmcnt(4)" ::: "memory");
        else                 asm volatile("s_waitcnt vmcnt(0)" ::: "memory");
        __builtin_amdgcn_s_barrier();          // all waves' vmcnt passed
        __builtin_amdgcn_sched_barrier(0);     // no ds_read hoists above

        const unsigned short* __restrict__ Ab = As[buf];
        const unsigned short* __restrict__ Bb = Bs[buf];
        const int k0n  = (T + 3) << 5;
        const int bufn = (T + 3) & 3;          // != buf; == (T-1)&3 (dead)

        // ---- phase 1: A-frags 0-3 + all B-frags, 16 MFMA ----
        bf16x8 af[4], bfr[4], af2[4];
#pragma unroll
        for (int i = 0; i < 4; ++i) {
            const int ra = wm + i * 16 + ln15;
            af[i] = *reinterpret_cast<const bf16x8*>(
                &Ab[(ra * 32 + kof) ^ (((ra >> 1) & 3) << 3)]);
            const int rb = wn + i * 16 + ln15;
            bfr[i] = *reinterpret_cast<const bf16x8*>(
                &Bb[(rb * 32 + kof) ^ (((rb >> 1) & 3) << 3)]);
        }
        if (T + 3 < NT) stage(bufn, k0n, 0);
        __builtin_amdgcn_s_barrier();
        __builtin_amdgcn_s_setprio(1);
#pragma unroll
        for (int i = 0; i < 4; ++i)
#pragma unroll
            for (int j = 0; j < 4; ++j)
                acc[i][j] = __builtin_amdgcn_mfma_f32_16x16x32_bf16(
                    af[i], bfr[j], acc[i][j], 0, 0, 0);
        __builtin_amdgcn_s_setprio(0);
        __builtin_amdgcn_sched_barrier(0);

        // ---- phase 2: A-frags 4-7 (reuse B-frags), 16 MFMA ----
#pragma unroll
        for (int i = 0; i < 4; ++i) {
            const int ra = wm + 64 + i * 16 + ln15;
            af2[i] = *reinterpret_cast<const bf16x8*>(
                &Ab[(ra * 32 + kof) ^ (((ra >> 1) & 3) << 3)]);
        }
        if (T + 3 < NT) stage(bufn, k0n, 1);
        __builtin_amdgcn_s_barrier();
        __builtin_amdgcn_s_setprio(1);
#pragma unroll
        for (int i = 0; i < 4; ++i)
#pragma unroll
            for (int j = 0; j < 4; ++j)
                acc[4 + i][j] = __builtin_amdgcn_mfma_f32_16x16x32_bf16(
                    af2[i], bfr[j], acc[4 + i][j], 0, 0, 0);
        __builtin_amdgcn_s_setprio(0);
        __builtin_amdgcn_sched_barrier(0);
    }

    // epilogue: C/D layout col = lane&15, row = quad*4 + reg
#pragma unroll
    for (int i = 0; i < 8; ++i) {
        const int gm = mBase + wm + i * 16 + quad * 4;
#pragma unroll
        for (int j = 0; j < 4; ++j) {
            const int gn = nBase + wn + j * 16 + ln15;
            const float bv = bias ? bias[gn] : 0.f;
#pragma unroll
            for (int r = 0; r < 4; ++r)
                C[(size_t)(gm + r) * ldc + gn] = f2bf(acc[i][j][r] + bv);
        }
    }
}

// ---------------------------------------------------------------------------
// C = A @ W^T + bias GEMM, bf16 inputs, DOUBLE-BUFFERED async LDS staging.
// Block tile 128x128, BK=64, 256 threads = 4 waves 2x2, wave does 64x64.
// T1 XCD swizzle (requires grid nwg % 8 == 0).
// ---------------------------------------------------------------------------
template <int ACT, typename OutT>
__global__ __launch_bounds__(256) void gemm_bt(
    const __hip_bfloat16* __restrict__ A, int lda,
    const __hip_bfloat16* __restrict__ W, int ldw,
    const float* __restrict__ bias,
    OutT* __restrict__ C, int ldc, int K)
{
    __shared__ __align__(16) unsigned short AsU[2][128 * 64];
    __shared__ __align__(16) unsigned short BsU[2][128 * 64];

    const int t     = threadIdx.x;
    const int nwg   = gridDim.x * gridDim.y;
    const int orig  = blockIdx.y * gridDim.x + blockIdx.x;
    const int swz   = (orig & 7) * (nwg >> 3) + (orig >> 3);
    const int mBase = (swz / gridDim.x) * 128;
    const int nBase = (swz % gridDim.x) * 128;
    const int wave  = t >> 6;
    const int lane  = t & 63;
    const int wm    = (wave >> 1) * 64;
    const int wn    = (wave & 1) * 64;
    const int ln15  = lane & 15;
    const int quad  = lane >> 4;

    f32x4 acc[4][4];
    const f32x4 vzero = {0.f, 0.f, 0.f, 0.f};
#pragma unroll
    for (int i = 0; i < 4; ++i)
#pragma unroll
        for (int j = 0; j < 4; ++j) acc[i][j] = vzero;

    auto stage = [&](int buf, int k0) {
#pragma unroll
        for (int i = 0; i < 4; ++i) {
            int idx = i * 256 + t;
            int r = idx >> 3;
            int c = (idx & 7) << 3;
            async16(&AsU[buf][idx * 8], A + (size_t)(mBase + r) * lda + k0 + c);
            async16(&BsU[buf][idx * 8], W + (size_t)(nBase + r) * ldw + k0 + c);
        }
    };

    const int nIter = K >> 6;
    stage(0, 0);

    for (int it = 0; it < nIter; ++it) {
        __syncthreads();   // buf[it&1] resident; prior reads of other buf done
        if (it + 1 < nIter) stage((it + 1) & 1, (it + 1) << 6);
        const unsigned short* As = AsU[it & 1];
        const unsigned short* Bs = BsU[it & 1];

#pragma unroll
        for (int kk = 0; kk < 64; kk += 32) {
            const int kof = kk + quad * 8;
            bf16x8 af[4], bfr[4];
#pragma unroll
            for (int i = 0; i < 4; ++i) {
                af[i]  = *reinterpret_cast<const bf16x8*>(&As[(wm + i * 16 + ln15) * 64 + kof]);
                bfr[i] = *reinterpret_cast<const bf16x8*>(&Bs[(wn + i * 16 + ln15) * 64 + kof]);
            }
#pragma unroll
            for (int i = 0; i < 4; ++i)
#pragma unroll
                for (int j = 0; j < 4; ++j)
                    acc[i][j] = __builtin_amdgcn_mfma_f32_16x16x32_bf16(af[i], bfr[j], acc[i][j], 0, 0, 0);
        }
    }

    // epilogue: C/D layout col = lane&15, row = quad*4 + reg
#pragma unroll
    for (int i = 0; i < 4; ++i) {
        const int gm = mBase + wm + i * 16 + quad * 4;
#pragma unroll
        for (int j = 0; j < 4; ++j) {
            const int gn = nBase + wn + j * 16 + ln15;
            const float bv = bias ? bias[gn] : 0.f;
#pragma unroll
            for (int r = 0; r < 4; ++r) {
                float v = acc[i][j][r] + bv;
                if (ACT == 1) v = softplusf(v);
                storeOut(C, (size_t)(gm + r) * ldc + gn, v);
            }
        }
    }
}

// ---------------------------------------------------------------------------
// Split-K variant: grid (nx, ny, SLICES); slice z handles K-range
// [z*K/SLICES, (z+1)*K/SLICES), stores fp32 partial at part + z*sliceElems.
// ---------------------------------------------------------------------------
__global__ __launch_bounds__(256) void gemm_bt_sk(
    const __hip_bfloat16* __restrict__ A, int lda,
    const __hip_bfloat16* __restrict__ W, int ldw,
    float* __restrict__ part, int ldc, int K, int slices, int sliceElems)
{
    __shared__ __align__(16) unsigned short AsU[2][128 * 64];
    __shared__ __align__(16) unsigned short BsU[2][128 * 64];

    const int t     = threadIdx.x;
    const int mBase = blockIdx.y * 128;
    const int nBase = blockIdx.x * 128;
    const int kLen  = K / slices;
    const int kOff  = blockIdx.z * kLen;
    const int wave  = t >> 6;
    const int lane  = t & 63;
    const int wm    = (wave >> 1) * 64;
    const int wn    = (wave & 1) * 64;
    const int ln15  = lane & 15;
    const int quad  = lane >> 4;

    f32x4 acc[4][4];
    const f32x4 vzero = {0.f, 0.f, 0.f, 0.f};
#pragma unroll
    for (int i = 0; i < 4; ++i)
#pragma unroll
        for (int j = 0; j < 4; ++j) acc[i][j] = vzero;

    auto stage = [&](int buf, int k0) {
#pragma unroll
        for (int i = 0; i < 4; ++i) {
            int idx = i * 256 + t;
            int r = idx >> 3;
            int c = (idx & 7) << 3;
            async16(&AsU[buf][idx * 8], A + (size_t)(mBase + r) * lda + k0 + c);
            async16(&BsU[buf][idx * 8], W + (size_t)(nBase + r) * ldw + k0 + c);
        }
    };

    const int nIter = kLen >> 6;
    stage(0, kOff);

    for (int it = 0; it < nIter; ++it) {
        __syncthreads();
        if (it + 1 < nIter) stage((it + 1) & 1, kOff + ((it + 1) << 6));
        const unsigned short* As = AsU[it & 1];
        const unsigned short* Bs = BsU[it & 1];

#pragma unroll
        for (int kk = 0; kk < 64; kk += 32) {
            const int kof = kk + quad * 8;
            bf16x8 af[4], bfr[4];
#pragma unroll
            for (int i = 0; i < 4; ++i) {
                af[i]  = *reinterpret_cast<const bf16x8*>(&As[(wm + i * 16 + ln15) * 64 + kof]);
                bfr[i] = *reinterpret_cast<const bf16x8*>(&Bs[(wn + i * 16 + ln15) * 64 + kof]);
            }
#pragma unroll
            for (int i = 0; i < 4; ++i)
#pragma unroll
                for (int j = 0; j < 4; ++j)
                    acc[i][j] = __builtin_amdgcn_mfma_f32_16x16x32_bf16(af[i], bfr[j], acc[i][j], 0, 0, 0);
        }
    }

    float* Cp = part + (size_t)blockIdx.z * sliceElems;
#pragma unroll
    for (int i = 0; i < 4; ++i) {
        const int gm = mBase + wm + i * 16 + quad * 4;
#pragma unroll
        for (int j = 0; j < 4; ++j) {
            const int gn = nBase + wn + j * 16 + ln15;
#pragma unroll
            for (int r = 0; r < 4; ++r)
                Cp[(size_t)(gm + r) * ldc + gn] = acc[i][j][r];
        }
    }
}

// sum 8 fp32 partials -> bf16 proj.  total = 2048*256 elems.
__global__ __launch_bounds__(256) void reduce_proj(
    const float* __restrict__ part, __hip_bfloat16* __restrict__ proj)
{
    int i = blockIdx.x * 256 + threadIdx.x;
    float s = 0.f;
#pragma unroll
    for (int z = 0; z < 8; ++z) s += part[(size_t)z * 524288 + i];
    proj[i] = f2bf(s);
}

// ---------------------------------------------------------------------------
// fp32 -> bf16 cast, 8 elems/thread (used for w_out after proj partials die).
// ---------------------------------------------------------------------------
__global__ __launch_bounds__(256) void cast_f32_bf16(
    const float* __restrict__ in, __hip_bfloat16* __restrict__ out)
{
    cast8(in, out, (size_t)blockIdx.x * 256 + threadIdx.x);
}

// ---------------------------------------------------------------------------
// FUSED prep: blocks [0,2048) cast u; [2048,10240) cast w_in;
// [10240,14336) build wcat; [14336,14592) cast w_dt.  One dispatch.
// ---------------------------------------------------------------------------
__global__ __launch_bounds__(256) void prep_all(
    const float* __restrict__ u, const float* __restrict__ w_in,
    const float* __restrict__ w_xdt, const float* __restrict__ w_xb,
    const float* __restrict__ w_xc, const float* __restrict__ w_dt,
    __hip_bfloat16* __restrict__ u_bf, __hip_bfloat16* __restrict__ w_in_bf,
    __hip_bfloat16* __restrict__ wcat, __hip_bfloat16* __restrict__ w_dt_bf)
{
    const int blk = blockIdx.x;
    const int t   = threadIdx.x;
    if (blk < 2048) {
        cast8(u, u_bf, (size_t)blk * 256 + t);
    } else if (blk < 10240) {
        cast8(w_in, w_in_bf, (size_t)(blk - 2048) * 256 + t);
    } else if (blk < 14336) {
        const int tid = (blk - 10240) * 256 + t;
        const int r = tid >> 12;
        const int c = tid & 4095;
        float v = 0.f;
        if (r < 128)      v = w_xdt[r * 4096 + c];
        else if (r < 144) v = w_xb[(r - 128) * 4096 + c];
        else if (r < 160) v = w_xc[(r - 144) * 4096 + c];
        wcat[tid] = f2bf(v);
    } else {
        cast8(w_dt, w_dt_bf, (size_t)(blk - 14336) * 256 + t);
    }
}

// ---------------------------------------------------------------------------
// Vectorized causal depthwise conv (win 4, left pad 3) + bias + silu over
// xz[:, :4096] -> xc, AND silu over xz[:, 4096:] IN PLACE (z-gate precompute
// for the scan).  8 outputs per thread, uint4 loads/stores.
// ---------------------------------------------------------------------------
__global__ __launch_bounds__(256) void conv_siluz(
    const __hip_bfloat16* __restrict__ xzr,
    __hip_bfloat16* __restrict__ xzw,          // same buffer, z-half writes
    const float* __restrict__ conv_w,
    const float* __restrict__ conv_b,
    __hip_bfloat16* __restrict__ xc)
{
    const int tid = blockIdx.x * 256 + threadIdx.x;
    if (tid < (1 << 20)) {
        const int row = tid >> 9;            // 0..2047 (b*1024 + l)
        const int d8  = (tid & 511) << 3;    // 0..4088 step 8
        const int l   = row & 1023;
        uint4 tv[4];
#pragma unroll
        for (int k = 0; k < 4; ++k) {
            const int ll = l - 3 + k;
            if (ll >= 0)
                tv[k] = *reinterpret_cast<const uint4*>(
                    &xzr[(size_t)(row - 3 + k) * 8192 + d8]);
            else
                tv[k] = make_uint4(0u, 0u, 0u, 0u);   // bf16 zeros
        }
        const float4 b0 = *reinterpret_cast<const float4*>(&conv_b[d8]);
        const float4 b1 = *reinterpret_cast<const float4*>(&conv_b[d8 + 4]);
        const unsigned short* t0 = (const unsigned short*)&tv[0];
        const unsigned short* t1 = (const unsigned short*)&tv[1];
        const unsigned short* t2 = (const unsigned short*)&tv[2];
        const unsigned short* t3 = (const unsigned short*)&tv[3];
        unsigned short o[8];
#pragma unroll
        for (int j = 0; j < 8; ++j) {
            const float4 w = *reinterpret_cast<const float4*>(&conv_w[(d8 + j) * 4]);
            float acc = (j < 4) ? ((const float*)&b0)[j] : ((const float*)&b1)[j - 4];
            acc += bfu2f(t0[j]) * w.x;
            acc += bfu2f(t1[j]) * w.y;
            acc += bfu2f(t2[j]) * w.z;
            acc += bfu2f(t3[j]) * w.w;
            o[j] = f2bfu(siluf(acc));
        }
        *reinterpret_cast<uint4*>(&xc[(size_t)row * 4096 + d8]) =
            *reinterpret_cast<const uint4*>(o);
    } else {
        const int zi  = tid - (1 << 20);
        const int row = zi >> 9;
        const int d8  = (zi & 511) << 3;
        const size_t a = (size_t)row * 8192 + 4096 + d8;
        const uint4 v = *reinterpret_cast<const uint4*>(&xzr[a]);
        const unsigned short* zv = (const unsigned short*)&v;
        unsigned short o[8];
#pragma unroll
        for (int j = 0; j < 8; ++j)
            o[j] = f2bfu(siluf(bfu2f(zv[j])));
        *reinterpret_cast<uint4*>(&xzw[a]) = *reinterpret_cast<const uint4*>(o);
    }
}

// ---------------------------------------------------------------------------
// selective scan with FUSED dt computation, 16 lanes/channel.
// 16 channels/block, 512 blocks, 256 threads.  LDS ~65.5 KB -> 2 blocks/CU
// (2 waves/SIMD).  Per chunk (128 t): stage proj[:, :128] chunk into s_pa
// (XOR-swizzled via pre-swizzled async16 source), MFMA [128t x 16d] dt-tile
// against s_wd (w_dt rows), softplus -> s_dt[d][t]; then the scan.
// z-half of xz holds PRE-GATED silu(z).
// ---------------------------------------------------------------------------
#define SCAN_T 128
#define ST4 132
#define ST2 136

__global__ __launch_bounds__(256) void scan_kernel(
    const __hip_bfloat16* __restrict__ proj,   // [2048,256]; dt-K at 0, B at 128, C at 144
    __hip_bfloat16* xcyg,                      // [2048, 4096] bf16 in/out
    const __hip_bfloat16* __restrict__ xz,     // [2048, 8192]; zg at 4096+d
    const __hip_bfloat16* __restrict__ wdt,    // [4096, 128] bf16
    const float* __restrict__ bdt,             // [4096] fp32
    const float* __restrict__ A_log,           // [4096, 16] fp32
    const float* __restrict__ Dp)              // [4096] fp32
{
    __shared__ __align__(16) float          s_dt[16 * ST4];   // [d][time]
    __shared__ __align__(16) unsigned short s_x [16 * ST2];
    __shared__ __align__(16) unsigned short s_z [16 * ST2];
    __shared__ __align__(16) unsigned short s_B [16 * ST2];   // [state][time]
    __shared__ __align__(16) unsigned short s_C [16 * ST2];
    __shared__ __align__(16) unsigned short s_y [16 * ST2];
    __shared__ __align__(16) unsigned short s_pa[128 * 128];  // proj chunk [t][k], swz
    __shared__ __align__(16) unsigned short s_wd[16 * 128];   // w_dt [d][k], swz

    const int t    = threadIdx.x;
    const int g    = t >> 4;         // channel in block, 0..15
    const int n    = t & 15;         // state
    const int wave = t >> 6;
    const int lane = t & 63;
    const int ln15 = lane & 15;
    const int quad = lane >> 4;
    const int wm32 = wave * 32;      // wave's 32-row t-stripe of the dt tile
    const int ch0  = blockIdx.x * 16;
    const int b    = ch0 >> 12;
    const int d0   = ch0 & 4095;
    const int d    = d0 + g;

    const float A2   = -__expf(A_log[d * 16 + n]) * 1.44269504f;
    const float Dpar = Dp[d];
    const size_t rowBase = (size_t)b * 1024;
    const float bdtv = bdt[d0 + ln15];   // lane's d-column of the dt tile

    // stage w_dt rows d0..d0+15 once (XOR-swizzled source, linear LDS dest)
    {
        const int idx = t;               // 256 slots of 16B = 16 rows x 128
        const int le  = (idx * 8) ^ (((idx >> 4) & 7) << 3);
        async16(&s_wd[idx * 8], &wdt[(size_t)(d0 + (idx >> 4)) * 128 + (le & 127)]);
    }

    // staging thread mappings (128 time-rows per chunk)
    const int lrow = t >> 1;             // 0..127
    const int lh8  = (t & 1) << 3;       // 0 or 8

    uint4 rx, rz, rBv, rCv;
    auto load_chunk = [&](int t0) {
        rx  = *reinterpret_cast<const uint4*>(
            &xcyg[(rowBase + t0 + lrow) * 4096 + d0 + lh8]);
        rz  = *reinterpret_cast<const uint4*>(
            &xz[(rowBase + t0 + lrow) * 8192 + 4096 + d0 + lh8]);
        rBv = *reinterpret_cast<const uint4*>(
            &proj[(rowBase + t0 + lrow) * 256 + 128 + lh8]);
        rCv = *reinterpret_cast<const uint4*>(
            &proj[(rowBase + t0 + lrow) * 256 + 144 + lh8]);
    };

    load_chunk(0);
    float h = 0.f;

#pragma unroll 1
    for (int c = 0; c < 1024 / SCAN_T; ++c) {
        const int t0 = c * SCAN_T;
        __syncthreads();                 // prior chunk's LDS reads complete

        // stage proj chunk rows t0..t0+127, cols 0..127 (async -> s_pa)
#pragma unroll
        for (int s = 0; s < 8; ++s) {
            const int idx = s * 256 + t;
            const int le  = (idx * 8) ^ (((idx >> 4) & 7) << 3);
            async16(&s_pa[idx * 8],
                    &proj[(rowBase + t0 + (idx >> 4)) * 256 + (le & 127)]);
        }
        // write prefetched x/z/B/C regs into LDS (transposed)
        {
            const unsigned short* px = (const unsigned short*)&rx;
            const unsigned short* pz = (const unsigned short*)&rz;
            const unsigned short* pB = (const unsigned short*)&rBv;
            const unsigned short* pC = (const unsigned short*)&rCv;
#pragma unroll
            for (int jj = 0; jj < 8; ++jj) {
                s_x[(lh8 + jj) * ST2 + lrow] = px[jj];
                s_z[(lh8 + jj) * ST2 + lrow] = pz[jj];
                s_B[(lh8 + jj) * ST2 + lrow] = pB[jj];
                s_C[(lh8 + jj) * ST2 + lrow] = pC[jj];
            }
        }
        __syncthreads();                 // drains vmcnt: s_pa/s_wd resident
        if (c + 1 < 1024 / SCAN_T) load_chunk(t0 + SCAN_T);

        // ---- fused dt tile: [128 t x 16 d] = softplus(projK @ wdt^T + bdt)
        {
            f32x4 dacc[2];
            const f32x4 vz4 = {0.f, 0.f, 0.f, 0.f};
            dacc[0] = vz4; dacc[1] = vz4;
#pragma unroll
            for (int ks = 0; ks < 4; ++ks) {
                const int kof = ks * 32 + quad * 8;
                bf16x8 paf[2], wbf;
#pragma unroll
                for (int i = 0; i < 2; ++i) {
                    const int ra = wm32 + i * 16 + ln15;
                    paf[i] = *reinterpret_cast<const bf16x8*>(
                        &s_pa[(ra * 128 + kof) ^ ((ra & 7) << 3)]);
                }
                {
                    const int rb = ln15;
                    wbf = *reinterpret_cast<const bf16x8*>(
                        &s_wd[(rb * 128 + kof) ^ ((rb & 7) << 3)]);
                }
#pragma unroll
                for (int i = 0; i < 2; ++i)
                    dacc[i] = __builtin_amdgcn_mfma_f32_16x16x32_bf16(
                        paf[i], wbf, dacc[i], 0, 0, 0);
            }
            // epilogue: C[m=t, n=d]; col=ln15, row=quad*4+r -> s_dt[d][t]
#pragma unroll
            for (int i = 0; i < 2; ++i) {
                const int tb = wm32 + i * 16 + quad * 4;
                const int dd = ln15;
                f32x4 w;
#pragma unroll
                for (int r = 0; r < 4; ++r)
                    w[r] = softplus_fast(dacc[i][r] + bdtv);
                *reinterpret_cast<f32x4*>(&s_dt[dd * ST4 + tb]) = w;
            }
        }
        __syncthreads();                 // s_dt visible to all waves

#pragma unroll 1
        for (int l0 = 0; l0 < SCAN_T; l0 += 8) {
            const uint4 vx = *reinterpret_cast<const uint4*>(&s_x[g * ST2 + l0]);
            const uint4 vz = *reinterpret_cast<const uint4*>(&s_z[g * ST2 + l0]);
            const uint4 vB = *reinterpret_cast<const uint4*>(&s_B[n * ST2 + l0]);
            const uint4 vC = *reinterpret_cast<const uint4*>(&s_C[n * ST2 + l0]);
            const float4 vd0 = *reinterpret_cast<const float4*>(&s_dt[g * ST4 + l0]);
            const float4 vd1 = *reinterpret_cast<const float4*>(&s_dt[g * ST4 + l0 + 4]);
            const unsigned short* ux = (const unsigned short*)&vx;
            const unsigned short* uz = (const unsigned short*)&vz;
            const unsigned short* uB = (const unsigned short*)&vB;
            const unsigned short* uC = (const unsigned short*)&vC;
            const float* fd0 = (const float*)&vd0;
            const float* fd1 = (const float*)&vd1;
            unsigned short y8[8];
#pragma unroll
            for (int j = 0; j < 8; ++j) {
                const float dtv = (j < 4) ? fd0[j] : fd1[j - 4];
                const float xv  = bfu2f(ux[j]);
                const float Bn  = bfu2f(uB[j]);
                const float Cn  = bfu2f(uC[j]);
                const float e   = __builtin_amdgcn_exp2f(dtv * A2);
                h = fmaf(h, e, (xv * dtv) * Bn);
                float p = h * Cn;
                p = dppadd<0xB1>(p);
                p = dppadd<0x4E>(p);
                p = dppadd<0x141>(p);
                p = dppadd<0x140>(p);
                if (n == 0) {
                    const float zgv = bfu2f(uz[j]);   // pre-gated silu(z)
                    y8[j] = f2bfu((p + Dpar * xv) * zgv);
                }
            }
            if (n == 0)
                *reinterpret_cast<uint4*>(&s_y[g * ST2 + l0]) =
                    *reinterpret_cast<const uint4*>(y8);
        }
        __syncthreads();

        {
            unsigned short tmp[8];
#pragma unroll
            for (int jj = 0; jj < 8; ++jj) tmp[jj] = s_y[(lh8 + jj) * ST2 + lrow];
            *reinterpret_cast<uint4*>(
                &xcyg[(rowBase + t0 + lrow) * 4096 + d0 + lh8]) =
                *reinterpret_cast<const uint4*>(tmp);
        }
    }
}

// ---------------------------------------------------------------------------
extern "C" void kernel_launch(void* const* d_in, const int* in_sizes, int n_in,
                              void* d_out, int out_size, void* d_ws, size_t ws_size,
                              hipStream_t stream)
{
    const float* u      = (const float*)d_in[0];
    const float* w_in   = (const float*)d_in[1];
    const float* b_in   = (const float*)d_in[2];
    const float* w_out  = (const float*)d_in[3];
    const float* b_out  = (const float*)d_in[4];
    const float* w_dt   = (const float*)d_in[5];
    const float* b_dt   = (const float*)d_in[6];
    const float* w_xdt  = (const float*)d_in[7];
    const float* w_xb   = (const float*)d_in[8];
    const float* w_xc   = (const float*)d_in[9];
    const float* conv_w = (const float*)d_in[10];
    const float* conv_b = (const float*)d_in[11];
    const float* A_log  = (const float*)d_in[12];
    const float* D_par  = (const float*)d_in[13];
    float* out = (float*)d_out;

    char* ws = (char*)d_ws;
    __hip_bfloat16* xz    = (__hip_bfloat16*)(ws);             // [2048,8192] 33.5 MB
    __hip_bfloat16* xc    = (__hip_bfloat16*)(ws + 33554432);  // [2048,4096] 16.8 MB
    __hip_bfloat16* u_bf  = (__hip_bfloat16*)(ws + 33554432);  // dead before xc written
    __hip_bfloat16* wcat  = (__hip_bfloat16*)(ws + 50331648);  // [256,4096]  2.1 MB
    __hip_bfloat16* w_dt_bf = (__hip_bfloat16*)(ws + 52428800);// [4096,128]  1.0 MB
    __hip_bfloat16* proj  = (__hip_bfloat16*)(ws + 51380224);  // [2048,256]  1.0 MB (inside wcat pad? NO -- see below)
    __hip_bfloat16* w_in_bf  = (__hip_bfloat16*)(ws + 53477376); // [8192,2048] bf16 33.5MB
    float*          projPart = (float*)(ws + 53477376);         // [8,2048,256] 16.8 MB (after w_in_bf dead)
    __hip_bfloat16* w_out_bf = (__hip_bfloat16*)(ws + 53477376); // after projPart dead
    // NOTE: wcat occupies [50331648, 52428800) (2.1 MB).  w_dt_bf now lives at
    // [52428800, 53477376) (1.0 MB) -- BOTH live from prep_all onward, no alias.
    // proj moved into the tail of the xc region?  NO: keep proj in its own slot.
    // Layout audit (live ranges):
    //   [0,        33554432)  xz            (step2 .. scan)
    //   [33554432, 50331648)  u_bf -> xc    (u_bf dead after step2; xc from step3)
    //   [50331648, 52428800)  wcat          (prep .. step4)
    //   [52428800, 53477376)  w_dt_bf       (prep .. scan)   [was proj's slot]
    //   [53477376, 70254592)  w_in_bf lower / projPart lower / w_out_bf
    //   [70254592, 87031808)  w_in_bf upper / projPart upper
    //   proj [2048,256] 1.0 MB -> placed at [87031808, 88080384)  (+1 MB ws)
    __hip_bfloat16* proj2 = (__hip_bfloat16*)(ws + 87031808);
    proj = proj2;
    // total 88.1 MB

    // 0+1. fused prep: cast u, cast w_in, build wcat, cast w_dt (1 dispatch)
    prep_all<<<14592, 256, 0, stream>>>(
        u, w_in, w_xdt, w_xb, w_xc, w_dt, u_bf, w_in_bf, wcat, w_dt_bf);

    // 2. in_proj: xz = u @ w_in^T + b_in   (M=2048, N=8192, K=2048)
    gemm256_bt<<<dim3(32, 8), 512, 0, stream>>>(
        u_bf, 2048, w_in_bf, 2048, b_in, xz, 8192, 2048);

    // 3. conv + silu -> xc; silu(z) in place over xz z-half (z-gate)
    conv_siluz<<<8192, 256, 0, stream>>>(xz, xz, conv_w, conv_b, xc);

    // 4. proj = xc @ wcat^T, split-K=8      (M=2048, N=256, K=4096)
    gemm_bt_sk<<<dim3(2, 16, 8), 256, 0, stream>>>(
        xc, 4096, wcat, 4096, projPart, 256, 4096, 8, 524288);
    reduce_proj<<<2048, 256, 0, stream>>>(projPart, proj);

    // 5. cast w_out into projPart region (dead after reduce_proj)
    cast_f32_bf16<<<4096, 256, 0, stream>>>(w_out, w_out_bf);

    // 6+7. selective scan with FUSED dt GEMM -> yg (in-place over xc)
    scan_kernel<<<512, 256, 0, stream>>>(
        proj, xc, xz, w_dt_bf, b_dt, A_log, D_par);

    // 8. out = yg @ w_out^T + b_out          (M=2048, N=2048, K=4096)
    gemm_bt<0, float><<<dim3(16, 16), 256, 0, stream>>>(
        xc, 4096, w_out_bf, 4096, b_out, out, 2048, 4096);
}

// Round 8
// 436.841 us; speedup vs baseline: 1.0618x; 1.0476x over previous
//
#include <hip/hip_runtime.h>
#include <hip/hip_bf16.h>

// UnifiedMambaBlock: B=2, L=1024, D_MODEL=2048, D_INNER=4096, N_STATE=16,
// DT_RANK=128, D_CONV=4.  ALL inputs/outputs fp32 (per reference dtypes).
// bf16 MFMA compute (no fp32 MFMA on CDNA4); fp32 epilogues.
//
// R15: scan issue diet #2:
//   - x/B/C stored as f32 in LDS (converted once at staging) -- inner loop
//     loses the per-step bf16 extract+convert chains
//   - defer-y: per-step sum captured via single cndmask (loop-invariant
//     compare); y computed once per 8-step body by lanes 0-7 in parallel,
//     replacing the exec-masked per-step epilogue (masked lanes still issue)
//   LDS 67072 -> 79360 B; 2 blocks/CU preserved (158.7 KB <= 160 KB).
// R14: prep fused to one dispatch; out-proj gains T1 XCD swizzle.
// R13: scan = 16 lanes/channel, fused dt MFMA tile, 512 blocks.
// R12: dt GEMM fused into scan (no dtb HBM round-trip).
// R10: z-gate silu(z) precomputed in conv kernel; conv vectorized.
// R8: in_proj GEMM = 256x256 deep-pipelined schedule.

#define DEV __device__ __forceinline__

typedef __attribute__((ext_vector_type(8))) __bf16 bf16x8;
typedef __attribute__((ext_vector_type(4))) float f32x4;
typedef unsigned int u32;

DEV float bf2f(__hip_bfloat16 x) { return __bfloat162float(x); }
DEV __hip_bfloat16 f2bf(float x) { return __float2bfloat16(x); }
DEV float bfu2f(unsigned short u) {
    union { u32 i; float f; } c; c.i = ((u32)u) << 16; return c.f;
}
DEV unsigned short f2bfu(float x) {
    __hip_bfloat16 h = __float2bfloat16(x);
    return *reinterpret_cast<unsigned short*>(&h);
}
DEV float softplusf(float v) { return v > 20.f ? v : log1pf(__expf(v)); }
DEV float siluf(float v) { return v / (1.f + __expf(-v)); }
// fast softplus: ln(1+e^v) via v_exp_f32/v_log_f32 (log2-based).
DEV float softplus_fast(float v) {
    if (v > 20.f) return v;
    const float e = __builtin_amdgcn_exp2f(v * 1.44269504f);
    return 0.69314718f * __builtin_amdgcn_logf(1.f + e);
}

DEV void storeOut(float* C, size_t off, float v) { C[off] = v; }
DEV void storeOut(__hip_bfloat16* C, size_t off, float v) { C[off] = f2bf(v); }

// async 16B global -> LDS (global_load_lds_dwordx4).
// LDS destination must be wave-uniform base + lane*16 (HW constraint).
DEV void async16(void* lds, const void* g) {
    __builtin_amdgcn_global_load_lds(
        (const __attribute__((address_space(1))) u32*)(unsigned long long)g,
        (__attribute__((address_space(3))) u32*)(u32)(unsigned long long)lds,
        16, 0, 0);
}

// DPP-based add of lane (permuted) value; reduction over 16-lane rows.
// MUST stay as the builtin: compiler inserts required DPP hazard nops.
template <int CTRL>
DEV float dppadd(float v) {
    int x = __builtin_amdgcn_update_dpp(
        0, __builtin_bit_cast(int, v), CTRL, 0xF, 0xF, true);
    return v + __builtin_bit_cast(float, x);
}

// vectorized 8-elem fp32->bf16 cast at element index i*8
DEV void cast8(const float* __restrict__ in, __hip_bfloat16* __restrict__ out,
               size_t i8) {
    const size_t i = i8 * 8;
    const float4 a = *reinterpret_cast<const float4*>(in + i);
    const float4 b = *reinterpret_cast<const float4*>(in + i + 4);
    unsigned short r[8];
    r[0] = f2bfu(a.x); r[1] = f2bfu(a.y); r[2] = f2bfu(a.z); r[3] = f2bfu(a.w);
    r[4] = f2bfu(b.x); r[5] = f2bfu(b.y); r[6] = f2bfu(b.z); r[7] = f2bfu(b.w);
    *reinterpret_cast<uint4*>(out + i) = *reinterpret_cast<uint4*>(r);
}

// ---------------------------------------------------------------------------
// 256x256-tile deep-pipelined GEMM: C = A @ W^T + bias (bf16 in, bf16 out).
// 512 threads = 8 waves (2M x 4N), per-wave 128x64 output, BK=32.
// 4 LDS buffers, prefetch distance 3 tiles, counted vmcnt, T2 swizzle, T5.
// ---------------------------------------------------------------------------
__global__ __launch_bounds__(512, 2) void gemm256_bt(
    const __hip_bfloat16* __restrict__ A, int lda,
    const __hip_bfloat16* __restrict__ W, int ldw,
    const float* __restrict__ bias,
    __hip_bfloat16* __restrict__ C, int ldc, int K)
{
    __shared__ __align__(16) unsigned short As[4][256 * 32];  // 64 KB
    __shared__ __align__(16) unsigned short Bs[4][256 * 32];  // 64 KB

    const int t    = threadIdx.x;
    // T1: bijective XCD swizzle (nwg % 8 == 0 guaranteed by launch shapes)
    const int nwg  = gridDim.x * gridDim.y;
    const int orig = blockIdx.y * gridDim.x + blockIdx.x;
    const int swz  = (orig & 7) * (nwg >> 3) + (orig >> 3);
    const int mBase = (swz / gridDim.x) * 256;
    const int nBase = (swz % gridDim.x) * 256;

    const int wave = t >> 6;
    const int lane = t & 63;
    const int wm   = (wave >> 2) * 128;   // 2 M wave-groups
    const int wn   = (wave & 3) * 64;     // 4 N wave-groups
    const int ln15 = lane & 15;
    const int quad = lane >> 4;
    const int kof  = quad * 8;

    f32x4 acc[8][4];
    const f32x4 vzero = {0.f, 0.f, 0.f, 0.f};
#pragma unroll
    for (int i = 0; i < 8; ++i)
#pragma unroll
        for (int j = 0; j < 4; ++j) acc[i][j] = vzero;

    auto stage = [&](int buf, int k0, int half) {
        const int idx = half * 512 + t;                 // 0..1023 -> 16B slot
        const int le  = (idx * 8) ^ (((idx >> 3) & 3) << 3);
        const int r   = le >> 5;
        const int c   = le & 31;
        async16(&As[buf][idx * 8], A + (size_t)(mBase + r) * lda + k0 + c);
        async16(&Bs[buf][idx * 8], W + (size_t)(nBase + r) * ldw + k0 + c);
    };

    const int NT = K >> 5;

#pragma unroll 1
    for (int p = 0; p < 3 && p < NT; ++p) {
        stage(p, p << 5, 0);
        stage(p, p << 5, 1);
    }

#pragma unroll 1
    for (int T = 0; T < NT; ++T) {
        const int buf = T & 3;
        if (T + 2 < NT)      asm volatile("s_waitcnt vmcnt(8)" ::: "memory");
        else if (T + 1 < NT) asm volatile("s_waitcnt vmcnt(4)" ::: "memory");
        else                 asm volatile("s_waitcnt vmcnt(0)" ::: "memory");
        __builtin_amdgcn_s_barrier();          // all waves' vmcnt passed
        __builtin_amdgcn_sched_barrier(0);     // no ds_read hoists above

        const unsigned short* __restrict__ Ab = As[buf];
        const unsigned short* __restrict__ Bb = Bs[buf];
        const int k0n  = (T + 3) << 5;
        const int bufn = (T + 3) & 3;          // != buf; == (T-1)&3 (dead)

        // ---- phase 1: A-frags 0-3 + all B-frags, 16 MFMA ----
        bf16x8 af[4], bfr[4], af2[4];
#pragma unroll
        for (int i = 0; i < 4; ++i) {
            const int ra = wm + i * 16 + ln15;
            af[i] = *reinterpret_cast<const bf16x8*>(
                &Ab[(ra * 32 + kof) ^ (((ra >> 1) & 3) << 3)]);
            const int rb = wn + i * 16 + ln15;
            bfr[i] = *reinterpret_cast<const bf16x8*>(
                &Bb[(rb * 32 + kof) ^ (((rb >> 1) & 3) << 3)]);
        }
        if (T + 3 < NT) stage(bufn, k0n, 0);
        __builtin_amdgcn_s_barrier();
        __builtin_amdgcn_s_setprio(1);
#pragma unroll
        for (int i = 0; i < 4; ++i)
#pragma unroll
            for (int j = 0; j < 4; ++j)
                acc[i][j] = __builtin_amdgcn_mfma_f32_16x16x32_bf16(
                    af[i], bfr[j], acc[i][j], 0, 0, 0);
        __builtin_amdgcn_s_setprio(0);
        __builtin_amdgcn_sched_barrier(0);

        // ---- phase 2: A-frags 4-7 (reuse B-frags), 16 MFMA ----
#pragma unroll
        for (int i = 0; i < 4; ++i) {
            const int ra = wm + 64 + i * 16 + ln15;
            af2[i] = *reinterpret_cast<const bf16x8*>(
                &Ab[(ra * 32 + kof) ^ (((ra >> 1) & 3) << 3)]);
        }
        if (T + 3 < NT) stage(bufn, k0n, 1);
        __builtin_amdgcn_s_barrier();
        __builtin_amdgcn_s_setprio(1);
#pragma unroll
        for (int i = 0; i < 4; ++i)
#pragma unroll
            for (int j = 0; j < 4; ++j)
                acc[4 + i][j] = __builtin_amdgcn_mfma_f32_16x16x32_bf16(
                    af2[i], bfr[j], acc[4 + i][j], 0, 0, 0);
        __builtin_amdgcn_s_setprio(0);
        __builtin_amdgcn_sched_barrier(0);
    }

    // epilogue: C/D layout col = lane&15, row = quad*4 + reg
#pragma unroll
    for (int i = 0; i < 8; ++i) {
        const int gm = mBase + wm + i * 16 + quad * 4;
#pragma unroll
        for (int j = 0; j < 4; ++j) {
            const int gn = nBase + wn + j * 16 + ln15;
            const float bv = bias ? bias[gn] : 0.f;
#pragma unroll
            for (int r = 0; r < 4; ++r)
                C[(size_t)(gm + r) * ldc + gn] = f2bf(acc[i][j][r] + bv);
        }
    }
}

// ---------------------------------------------------------------------------
// C = A @ W^T + bias GEMM, bf16 inputs, DOUBLE-BUFFERED async LDS staging.
// Block tile 128x128, BK=64, 256 threads = 4 waves 2x2, wave does 64x64.
// T1 XCD swizzle (requires grid nwg % 8 == 0).
// ---------------------------------------------------------------------------
template <int ACT, typename OutT>
__global__ __launch_bounds__(256) void gemm_bt(
    const __hip_bfloat16* __restrict__ A, int lda,
    const __hip_bfloat16* __restrict__ W, int ldw,
    const float* __restrict__ bias,
    OutT* __restrict__ C, int ldc, int K)
{
    __shared__ __align__(16) unsigned short AsU[2][128 * 64];
    __shared__ __align__(16) unsigned short BsU[2][128 * 64];

    const int t     = threadIdx.x;
    const int nwg   = gridDim.x * gridDim.y;
    const int orig  = blockIdx.y * gridDim.x + blockIdx.x;
    const int swz   = (orig & 7) * (nwg >> 3) + (orig >> 3);
    const int mBase = (swz / gridDim.x) * 128;
    const int nBase = (swz % gridDim.x) * 128;
    const int wave  = t >> 6;
    const int lane  = t & 63;
    const int wm    = (wave >> 1) * 64;
    const int wn    = (wave & 1) * 64;
    const int ln15  = lane & 15;
    const int quad  = lane >> 4;

    f32x4 acc[4][4];
    const f32x4 vzero = {0.f, 0.f, 0.f, 0.f};
#pragma unroll
    for (int i = 0; i < 4; ++i)
#pragma unroll
        for (int j = 0; j < 4; ++j) acc[i][j] = vzero;

    auto stage = [&](int buf, int k0) {
#pragma unroll
        for (int i = 0; i < 4; ++i) {
            int idx = i * 256 + t;
            int r = idx >> 3;
            int c = (idx & 7) << 3;
            async16(&AsU[buf][idx * 8], A + (size_t)(mBase + r) * lda + k0 + c);
            async16(&BsU[buf][idx * 8], W + (size_t)(nBase + r) * ldw + k0 + c);
        }
    };

    const int nIter = K >> 6;
    stage(0, 0);

    for (int it = 0; it < nIter; ++it) {
        __syncthreads();   // buf[it&1] resident; prior reads of other buf done
        if (it + 1 < nIter) stage((it + 1) & 1, (it + 1) << 6);
        const unsigned short* As = AsU[it & 1];
        const unsigned short* Bs = BsU[it & 1];

#pragma unroll
        for (int kk = 0; kk < 64; kk += 32) {
            const int kof = kk + quad * 8;
            bf16x8 af[4], bfr[4];
#pragma unroll
            for (int i = 0; i < 4; ++i) {
                af[i]  = *reinterpret_cast<const bf16x8*>(&As[(wm + i * 16 + ln15) * 64 + kof]);
                bfr[i] = *reinterpret_cast<const bf16x8*>(&Bs[(wn + i * 16 + ln15) * 64 + kof]);
            }
#pragma unroll
            for (int i = 0; i < 4; ++i)
#pragma unroll
                for (int j = 0; j < 4; ++j)
                    acc[i][j] = __builtin_amdgcn_mfma_f32_16x16x32_bf16(af[i], bfr[j], acc[i][j], 0, 0, 0);
        }
    }

    // epilogue: C/D layout col = lane&15, row = quad*4 + reg
#pragma unroll
    for (int i = 0; i < 4; ++i) {
        const int gm = mBase + wm + i * 16 + quad * 4;
#pragma unroll
        for (int j = 0; j < 4; ++j) {
            const int gn = nBase + wn + j * 16 + ln15;
            const float bv = bias ? bias[gn] : 0.f;
#pragma unroll
            for (int r = 0; r < 4; ++r) {
                float v = acc[i][j][r] + bv;
                if (ACT == 1) v = softplusf(v);
                storeOut(C, (size_t)(gm + r) * ldc + gn, v);
            }
        }
    }
}

// ---------------------------------------------------------------------------
// Split-K variant: grid (nx, ny, SLICES); slice z handles K-range
// [z*K/SLICES, (z+1)*K/SLICES), stores fp32 partial at part + z*sliceElems.
// ---------------------------------------------------------------------------
__global__ __launch_bounds__(256) void gemm_bt_sk(
    const __hip_bfloat16* __restrict__ A, int lda,
    const __hip_bfloat16* __restrict__ W, int ldw,
    float* __restrict__ part, int ldc, int K, int slices, int sliceElems)
{
    __shared__ __align__(16) unsigned short AsU[2][128 * 64];
    __shared__ __align__(16) unsigned short BsU[2][128 * 64];

    const int t     = threadIdx.x;
    const int mBase = blockIdx.y * 128;
    const int nBase = blockIdx.x * 128;
    const int kLen  = K / slices;
    const int kOff  = blockIdx.z * kLen;
    const int wave  = t >> 6;
    const int lane  = t & 63;
    const int wm    = (wave >> 1) * 64;
    const int wn    = (wave & 1) * 64;
    const int ln15  = lane & 15;
    const int quad  = lane >> 4;

    f32x4 acc[4][4];
    const f32x4 vzero = {0.f, 0.f, 0.f, 0.f};
#pragma unroll
    for (int i = 0; i < 4; ++i)
#pragma unroll
        for (int j = 0; j < 4; ++j) acc[i][j] = vzero;

    auto stage = [&](int buf, int k0) {
#pragma unroll
        for (int i = 0; i < 4; ++i) {
            int idx = i * 256 + t;
            int r = idx >> 3;
            int c = (idx & 7) << 3;
            async16(&AsU[buf][idx * 8], A + (size_t)(mBase + r) * lda + k0 + c);
            async16(&BsU[buf][idx * 8], W + (size_t)(nBase + r) * ldw + k0 + c);
        }
    };

    const int nIter = kLen >> 6;
    stage(0, kOff);

    for (int it = 0; it < nIter; ++it) {
        __syncthreads();
        if (it + 1 < nIter) stage((it + 1) & 1, kOff + ((it + 1) << 6));
        const unsigned short* As = AsU[it & 1];
        const unsigned short* Bs = BsU[it & 1];

#pragma unroll
        for (int kk = 0; kk < 64; kk += 32) {
            const int kof = kk + quad * 8;
            bf16x8 af[4], bfr[4];
#pragma unroll
            for (int i = 0; i < 4; ++i) {
                af[i]  = *reinterpret_cast<const bf16x8*>(&As[(wm + i * 16 + ln15) * 64 + kof]);
                bfr[i] = *reinterpret_cast<const bf16x8*>(&Bs[(wn + i * 16 + ln15) * 64 + kof]);
            }
#pragma unroll
            for (int i = 0; i < 4; ++i)
#pragma unroll
                for (int j = 0; j < 4; ++j)
                    acc[i][j] = __builtin_amdgcn_mfma_f32_16x16x32_bf16(af[i], bfr[j], acc[i][j], 0, 0, 0);
        }
    }

    float* Cp = part + (size_t)blockIdx.z * sliceElems;
#pragma unroll
    for (int i = 0; i < 4; ++i) {
        const int gm = mBase + wm + i * 16 + quad * 4;
#pragma unroll
        for (int j = 0; j < 4; ++j) {
            const int gn = nBase + wn + j * 16 + ln15;
#pragma unroll
            for (int r = 0; r < 4; ++r)
                Cp[(size_t)(gm + r) * ldc + gn] = acc[i][j][r];
        }
    }
}

// sum 8 fp32 partials -> bf16 proj.  total = 2048*256 elems.
__global__ __launch_bounds__(256) void reduce_proj(
    const float* __restrict__ part, __hip_bfloat16* __restrict__ proj)
{
    int i = blockIdx.x * 256 + threadIdx.x;
    float s = 0.f;
#pragma unroll
    for (int z = 0; z < 8; ++z) s += part[(size_t)z * 524288 + i];
    proj[i] = f2bf(s);
}

// ---------------------------------------------------------------------------
// fp32 -> bf16 cast, 8 elems/thread (used for w_out after proj partials die).
// ---------------------------------------------------------------------------
__global__ __launch_bounds__(256) void cast_f32_bf16(
    const float* __restrict__ in, __hip_bfloat16* __restrict__ out)
{
    cast8(in, out, (size_t)blockIdx.x * 256 + threadIdx.x);
}

// ---------------------------------------------------------------------------
// FUSED prep: blocks [0,2048) cast u; [2048,10240) cast w_in;
// [10240,14336) build wcat; [14336,14592) cast w_dt.  One dispatch.
// ---------------------------------------------------------------------------
__global__ __launch_bounds__(256) void prep_all(
    const float* __restrict__ u, const float* __restrict__ w_in,
    const float* __restrict__ w_xdt, const float* __restrict__ w_xb,
    const float* __restrict__ w_xc, const float* __restrict__ w_dt,
    __hip_bfloat16* __restrict__ u_bf, __hip_bfloat16* __restrict__ w_in_bf,
    __hip_bfloat16* __restrict__ wcat, __hip_bfloat16* __restrict__ w_dt_bf)
{
    const int blk = blockIdx.x;
    const int t   = threadIdx.x;
    if (blk < 2048) {
        cast8(u, u_bf, (size_t)blk * 256 + t);
    } else if (blk < 10240) {
        cast8(w_in, w_in_bf, (size_t)(blk - 2048) * 256 + t);
    } else if (blk < 14336) {
        const int tid = (blk - 10240) * 256 + t;
        const int r = tid >> 12;
        const int c = tid & 4095;
        float v = 0.f;
        if (r < 128)      v = w_xdt[r * 4096 + c];
        else if (r < 144) v = w_xb[(r - 128) * 4096 + c];
        else if (r < 160) v = w_xc[(r - 144) * 4096 + c];
        wcat[tid] = f2bf(v);
    } else {
        cast8(w_dt, w_dt_bf, (size_t)(blk - 14336) * 256 + t);
    }
}

// ---------------------------------------------------------------------------
// Vectorized causal depthwise conv (win 4, left pad 3) + bias + silu over
// xz[:, :4096] -> xc, AND silu over xz[:, 4096:] IN PLACE (z-gate precompute
// for the scan).  8 outputs per thread, uint4 loads/stores.
// ---------------------------------------------------------------------------
__global__ __launch_bounds__(256) void conv_siluz(
    const __hip_bfloat16* __restrict__ xzr,
    __hip_bfloat16* __restrict__ xzw,          // same buffer, z-half writes
    const float* __restrict__ conv_w,
    const float* __restrict__ conv_b,
    __hip_bfloat16* __restrict__ xc)
{
    const int tid = blockIdx.x * 256 + threadIdx.x;
    if (tid < (1 << 20)) {
        const int row = tid >> 9;            // 0..2047 (b*1024 + l)
        const int d8  = (tid & 511) << 3;    // 0..4088 step 8
        const int l   = row & 1023;
        uint4 tv[4];
#pragma unroll
        for (int k = 0; k < 4; ++k) {
            const int ll = l - 3 + k;
            if (ll >= 0)
                tv[k] = *reinterpret_cast<const uint4*>(
                    &xzr[(size_t)(row - 3 + k) * 8192 + d8]);
            else
                tv[k] = make_uint4(0u, 0u, 0u, 0u);   // bf16 zeros
        }
        const float4 b0 = *reinterpret_cast<const float4*>(&conv_b[d8]);
        const float4 b1 = *reinterpret_cast<const float4*>(&conv_b[d8 + 4]);
        const unsigned short* t0 = (const unsigned short*)&tv[0];
        const unsigned short* t1 = (const unsigned short*)&tv[1];
        const unsigned short* t2 = (const unsigned short*)&tv[2];
        const unsigned short* t3 = (const unsigned short*)&tv[3];
        unsigned short o[8];
#pragma unroll
        for (int j = 0; j < 8; ++j) {
            const float4 w = *reinterpret_cast<const float4*>(&conv_w[(d8 + j) * 4]);
            float acc = (j < 4) ? ((const float*)&b0)[j] : ((const float*)&b1)[j - 4];
            acc += bfu2f(t0[j]) * w.x;
            acc += bfu2f(t1[j]) * w.y;
            acc += bfu2f(t2[j]) * w.z;
            acc += bfu2f(t3[j]) * w.w;
            o[j] = f2bfu(siluf(acc));
        }
        *reinterpret_cast<uint4*>(&xc[(size_t)row * 4096 + d8]) =
            *reinterpret_cast<const uint4*>(o);
    } else {
        const int zi  = tid - (1 << 20);
        const int row = zi >> 9;
        const int d8  = (zi & 511) << 3;
        const size_t a = (size_t)row * 8192 + 4096 + d8;
        const uint4 v = *reinterpret_cast<const uint4*>(&xzr[a]);
        const unsigned short* zv = (const unsigned short*)&v;
        unsigned short o[8];
#pragma unroll
        for (int j = 0; j < 8; ++j)
            o[j] = f2bfu(siluf(bfu2f(zv[j])));
        *reinterpret_cast<uint4*>(&xzw[a]) = *reinterpret_cast<const uint4*>(o);
    }
}

// ---------------------------------------------------------------------------
// selective scan with FUSED dt computation, 16 lanes/channel.
// 16 channels/block, 512 blocks, 256 threads.  LDS 79360 B -> 2 blocks/CU.
// x/B/C stored f32 in LDS (converted at staging); per-step y epilogue
// replaced by cndmask capture + parallel tail on lanes 0-7 (defer-y).
// z-half of xz holds PRE-GATED silu(z).
// ---------------------------------------------------------------------------
#define SCAN_T 128
#define ST4 132
#define ST2 136

__global__ __launch_bounds__(256) void scan_kernel(
    const __hip_bfloat16* __restrict__ proj,   // [2048,256]; dt-K at 0, B at 128, C at 144
    __hip_bfloat16* xcyg,                      // [2048, 4096] bf16 in/out
    const __hip_bfloat16* __restrict__ xz,     // [2048, 8192]; zg at 4096+d
    const __hip_bfloat16* __restrict__ wdt,    // [4096, 128] bf16
    const float* __restrict__ bdt,             // [4096] fp32
    const float* __restrict__ A_log,           // [4096, 16] fp32
    const float* __restrict__ Dp)              // [4096] fp32
{
    __shared__ __align__(16) float          s_dt[16 * ST4];   // [d][time]
    __shared__ __align__(16) float          s_xf[16 * ST4];   // [d][time] f32
    __shared__ __align__(16) float          s_Bf[16 * ST4];   // [state][time] f32
    __shared__ __align__(16) float          s_Cf[16 * ST4];   // [state][time] f32
    __shared__ __align__(16) unsigned short s_z [16 * ST2];   // [d][time] bf16
    __shared__ __align__(16) unsigned short s_y [16 * ST2];
    __shared__ __align__(16) unsigned short s_pa[128 * 128];  // proj chunk [t][k], swz
    __shared__ __align__(16) unsigned short s_wd[16 * 128];   // w_dt [d][k], swz

    const int t    = threadIdx.x;
    const int g    = t >> 4;         // channel in block, 0..15
    const int n    = t & 15;         // state
    const int wave = t >> 6;
    const int lane = t & 63;
    const int ln15 = lane & 15;
    const int quad = lane >> 4;
    const int wm32 = wave * 32;      // wave's 32-row t-stripe of the dt tile
    const int ch0  = blockIdx.x * 16;
    const int b    = ch0 >> 12;
    const int d0   = ch0 & 4095;
    const int d    = d0 + g;

    const float A2   = -__expf(A_log[d * 16 + n]) * 1.44269504f;
    const float Dpar = Dp[d];
    const size_t rowBase = (size_t)b * 1024;
    const float bdtv = bdt[d0 + ln15];   // lane's d-column of the dt tile

    // stage w_dt rows d0..d0+15 once (XOR-swizzled source, linear LDS dest)
    {
        const int idx = t;               // 256 slots of 16B = 16 rows x 128
        const int le  = (idx * 8) ^ (((idx >> 4) & 7) << 3);
        async16(&s_wd[idx * 8], &wdt[(size_t)(d0 + (idx >> 4)) * 128 + (le & 127)]);
    }

    // staging thread mappings (128 time-rows per chunk)
    const int lrow = t >> 1;             // 0..127
    const int lh8  = (t & 1) << 3;       // 0 or 8

    uint4 rx, rz, rBv, rCv;
    auto load_chunk = [&](int t0) {
        rx  = *reinterpret_cast<const uint4*>(
            &xcyg[(rowBase + t0 + lrow) * 4096 + d0 + lh8]);
        rz  = *reinterpret_cast<const uint4*>(
            &xz[(rowBase + t0 + lrow) * 8192 + 4096 + d0 + lh8]);
        rBv = *reinterpret_cast<const uint4*>(
            &proj[(rowBase + t0 + lrow) * 256 + 128 + lh8]);
        rCv = *reinterpret_cast<const uint4*>(
            &proj[(rowBase + t0 + lrow) * 256 + 144 + lh8]);
    };

    load_chunk(0);
    float h = 0.f;

#pragma unroll 1
    for (int c = 0; c < 1024 / SCAN_T; ++c) {
        const int t0 = c * SCAN_T;
        __syncthreads();                 // prior chunk's LDS reads complete

        // stage proj chunk rows t0..t0+127, cols 0..127 (async -> s_pa)
#pragma unroll
        for (int s = 0; s < 8; ++s) {
            const int idx = s * 256 + t;
            const int le  = (idx * 8) ^ (((idx >> 4) & 7) << 3);
            async16(&s_pa[idx * 8],
                    &proj[(rowBase + t0 + (idx >> 4)) * 256 + (le & 127)]);
        }
        // write prefetched x/z/B/C regs into LDS (transposed; x/B/C -> f32)
        {
            const unsigned short* px = (const unsigned short*)&rx;
            const unsigned short* pz = (const unsigned short*)&rz;
            const unsigned short* pB = (const unsigned short*)&rBv;
            const unsigned short* pC = (const unsigned short*)&rCv;
#pragma unroll
            for (int jj = 0; jj < 8; ++jj) {
                s_xf[(lh8 + jj) * ST4 + lrow] = bfu2f(px[jj]);
                s_z [(lh8 + jj) * ST2 + lrow] = pz[jj];
                s_Bf[(lh8 + jj) * ST4 + lrow] = bfu2f(pB[jj]);
                s_Cf[(lh8 + jj) * ST4 + lrow] = bfu2f(pC[jj]);
            }
        }
        __syncthreads();                 // drains vmcnt: s_pa/s_wd resident
        if (c + 1 < 1024 / SCAN_T) load_chunk(t0 + SCAN_T);

        // ---- fused dt tile: [128 t x 16 d] = softplus(projK @ wdt^T + bdt)
        {
            f32x4 dacc[2];
            const f32x4 vz4 = {0.f, 0.f, 0.f, 0.f};
            dacc[0] = vz4; dacc[1] = vz4;
#pragma unroll
            for (int ks = 0; ks < 4; ++ks) {
                const int kof = ks * 32 + quad * 8;
                bf16x8 paf[2], wbf;
#pragma unroll
                for (int i = 0; i < 2; ++i) {
                    const int ra = wm32 + i * 16 + ln15;
                    paf[i] = *reinterpret_cast<const bf16x8*>(
                        &s_pa[(ra * 128 + kof) ^ ((ra & 7) << 3)]);
                }
                {
                    const int rb = ln15;
                    wbf = *reinterpret_cast<const bf16x8*>(
                        &s_wd[(rb * 128 + kof) ^ ((rb & 7) << 3)]);
                }
#pragma unroll
                for (int i = 0; i < 2; ++i)
                    dacc[i] = __builtin_amdgcn_mfma_f32_16x16x32_bf16(
                        paf[i], wbf, dacc[i], 0, 0, 0);
            }
            // epilogue: C[m=t, n=d]; col=ln15, row=quad*4+r -> s_dt[d][t]
#pragma unroll
            for (int i = 0; i < 2; ++i) {
                const int tb = wm32 + i * 16 + quad * 4;
                const int dd = ln15;
                f32x4 w;
#pragma unroll
                for (int r = 0; r < 4; ++r)
                    w[r] = softplus_fast(dacc[i][r] + bdtv);
                *reinterpret_cast<f32x4*>(&s_dt[dd * ST4 + tb]) = w;
            }
        }
        __syncthreads();                 // s_dt visible to all waves

#pragma unroll 1
        for (int l0 = 0; l0 < SCAN_T; l0 += 8) {
            const float4 vd0 = *reinterpret_cast<const float4*>(&s_dt[g * ST4 + l0]);
            const float4 vd1 = *reinterpret_cast<const float4*>(&s_dt[g * ST4 + l0 + 4]);
            const float4 vx0 = *reinterpret_cast<const float4*>(&s_xf[g * ST4 + l0]);
            const float4 vx1 = *reinterpret_cast<const float4*>(&s_xf[g * ST4 + l0 + 4]);
            const float4 vB0 = *reinterpret_cast<const float4*>(&s_Bf[n * ST4 + l0]);
            const float4 vB1 = *reinterpret_cast<const float4*>(&s_Bf[n * ST4 + l0 + 4]);
            const float4 vC0 = *reinterpret_cast<const float4*>(&s_Cf[n * ST4 + l0]);
            const float4 vC1 = *reinterpret_cast<const float4*>(&s_Cf[n * ST4 + l0 + 4]);
            const float* fd0 = (const float*)&vd0;
            const float* fd1 = (const float*)&vd1;
            const float* fx0 = (const float*)&vx0;
            const float* fx1 = (const float*)&vx1;
            const float* fB0 = (const float*)&vB0;
            const float* fB1 = (const float*)&vB1;
            const float* fC0 = (const float*)&vC0;
            const float* fC1 = (const float*)&vC1;
            float psum = 0.f;
#pragma unroll
            for (int j = 0; j < 8; ++j) {
                const float dtv = (j < 4) ? fd0[j] : fd1[j - 4];
                const float xv  = (j < 4) ? fx0[j] : fx1[j - 4];
                const float Bn  = (j < 4) ? fB0[j] : fB1[j - 4];
                const float Cn  = (j < 4) ? fC0[j] : fC1[j - 4];
                const float e   = __builtin_amdgcn_exp2f(dtv * A2);
                h = fmaf(h, e, (xv * dtv) * Bn);
                float p = h * Cn;
                p = dppadd<0xB1>(p);
                p = dppadd<0x4E>(p);
                p = dppadd<0x141>(p);
                p = dppadd<0x140>(p);
                psum = (n == j) ? p : psum;   // loop-invariant cmp, 1 cndmask
            }
            // defer-y tail: lanes 0-7 each emit y for one step
            if (n < 8) {
                const float xvn = s_xf[g * ST4 + l0 + n];
                const float zgv = bfu2f(s_z[g * ST2 + l0 + n]);
                s_y[g * ST2 + l0 + n] = f2bfu((psum + Dpar * xvn) * zgv);
            }
        }
        __syncthreads();

        {
            unsigned short tmp[8];
#pragma unroll
            for (int jj = 0; jj < 8; ++jj) tmp[jj] = s_y[(lh8 + jj) * ST2 + lrow];
            *reinterpret_cast<uint4*>(
                &xcyg[(rowBase + t0 + lrow) * 4096 + d0 + lh8]) =
                *reinterpret_cast<const uint4*>(tmp);
        }
    }
}

// ---------------------------------------------------------------------------
extern "C" void kernel_launch(void* const* d_in, const int* in_sizes, int n_in,
                              void* d_out, int out_size, void* d_ws, size_t ws_size,
                              hipStream_t stream)
{
    const float* u      = (const float*)d_in[0];
    const float* w_in   = (const float*)d_in[1];
    const float* b_in   = (const float*)d_in[2];
    const float* w_out  = (const float*)d_in[3];
    const float* b_out  = (const float*)d_in[4];
    const float* w_dt   = (const float*)d_in[5];
    const float* b_dt   = (const float*)d_in[6];
    const float* w_xdt  = (const float*)d_in[7];
    const float* w_xb   = (const float*)d_in[8];
    const float* w_xc   = (const float*)d_in[9];
    const float* conv_w = (const float*)d_in[10];
    const float* conv_b = (const float*)d_in[11];
    const float* A_log  = (const float*)d_in[12];
    const float* D_par  = (const float*)d_in[13];
    float* out = (float*)d_out;

    char* ws = (char*)d_ws;
    __hip_bfloat16* xz    = (__hip_bfloat16*)(ws);             // [2048,8192] 33.5 MB
    __hip_bfloat16* xc    = (__hip_bfloat16*)(ws + 33554432);  // [2048,4096] 16.8 MB
    __hip_bfloat16* u_bf  = (__hip_bfloat16*)(ws + 33554432);  // dead before xc written
    __hip_bfloat16* wcat  = (__hip_bfloat16*)(ws + 50331648);  // [256,4096]  2.1 MB
    __hip_bfloat16* w_dt_bf = (__hip_bfloat16*)(ws + 52428800);// [4096,128]  1.0 MB
    __hip_bfloat16* w_in_bf  = (__hip_bfloat16*)(ws + 53477376); // [8192,2048] bf16 33.5MB
    float*          projPart = (float*)(ws + 53477376);         // [8,2048,256] 16.8 MB (after w_in_bf dead)
    __hip_bfloat16* w_out_bf = (__hip_bfloat16*)(ws + 53477376); // after projPart dead
    __hip_bfloat16* proj  = (__hip_bfloat16*)(ws + 87031808);   // [2048,256] 1.0 MB
    // Layout audit (live ranges):
    //   [0,        33554432)  xz            (step2 .. scan)
    //   [33554432, 50331648)  u_bf -> xc    (u_bf dead after step2; xc from step3)
    //   [50331648, 52428800)  wcat          (prep .. step4)
    //   [52428800, 53477376)  w_dt_bf       (prep .. scan)
    //   [53477376, 87031808)  w_in_bf / projPart / w_out_bf (sequential reuse)
    //   [87031808, 88080384)  proj          (reduce_proj .. scan)
    // total 88.1 MB

    // 0+1. fused prep: cast u, cast w_in, build wcat, cast w_dt (1 dispatch)
    prep_all<<<14592, 256, 0, stream>>>(
        u, w_in, w_xdt, w_xb, w_xc, w_dt, u_bf, w_in_bf, wcat, w_dt_bf);

    // 2. in_proj: xz = u @ w_in^T + b_in   (M=2048, N=8192, K=2048)
    gemm256_bt<<<dim3(32, 8), 512, 0, stream>>>(
        u_bf, 2048, w_in_bf, 2048, b_in, xz, 8192, 2048);

    // 3. conv + silu -> xc; silu(z) in place over xz z-half (z-gate)
    conv_siluz<<<8192, 256, 0, stream>>>(xz, xz, conv_w, conv_b, xc);

    // 4. proj = xc @ wcat^T, split-K=8      (M=2048, N=256, K=4096)
    gemm_bt_sk<<<dim3(2, 16, 8), 256, 0, stream>>>(
        xc, 4096, wcat, 4096, projPart, 256, 4096, 8, 524288);
    reduce_proj<<<2048, 256, 0, stream>>>(projPart, proj);

    // 5. cast w_out into projPart region (dead after reduce_proj)
    cast_f32_bf16<<<4096, 256, 0, stream>>>(w_out, w_out_bf);

    // 6+7. selective scan with FUSED dt GEMM -> yg (in-place over xc)
    scan_kernel<<<512, 256, 0, stream>>>(
        proj, xc, xz, w_dt_bf, b_dt, A_log, D_par);

    // 8. out = yg @ w_out^T + b_out          (M=2048, N=2048, K=4096)
    gemm_bt<0, float><<<dim3(16, 16), 256, 0, stream>>>(
        xc, 4096, w_out_bf, 4096, b_out, out, 2048, 4096);
}

// Round 9
// 425.180 us; speedup vs baseline: 1.0910x; 1.0274x over previous
//
#include <hip/hip_runtime.h>
#include <hip/hip_bf16.h>

// UnifiedMambaBlock: B=2, L=1024, D_MODEL=2048, D_INNER=4096, N_STATE=16,
// DT_RANK=128, D_CONV=4.  ALL inputs/outputs fp32 (per reference dtypes).
// bf16 MFMA compute (no fp32 MFMA on CDNA4); fp32 epilogues.
//
// R16: scan issue diet #3:
//   - s_pa/s_wd LDS staging REMOVED: proj-chunk MFMA fragments have zero
//     intra-block reuse, so they load directly global->VGPR (proj is 1 MB,
//     L2/L3-resident across all 512 blocks); w_dt fragments are
//     chunk-invariant -> preloaded once into registers.  LDS 79.4->42.2 KB,
//     and the staging vmcnt drain at the mid-chunk barrier disappears.
//   - 4th DPP level dropped: (n&7)==j cndmask captures per-half-row sums;
//     one __shfl_xor(psum,8)+add per 8-step body combines halves in the
//     defer-y tail (replaces 16 inst/body with ~3).
// R15: x/B/C f32 in LDS; defer-y tail.            R14: fused prep; T1 swz.
// R13: 16 lanes/channel + fused dt MFMA tile.     R12: dt GEMM fused.
// R10: z-gate precompute; vectorized conv.        R8: 256^2 in_proj GEMM.

#define DEV __device__ __forceinline__

typedef __attribute__((ext_vector_type(8))) __bf16 bf16x8;
typedef __attribute__((ext_vector_type(4))) float f32x4;
typedef unsigned int u32;

DEV float bf2f(__hip_bfloat16 x) { return __bfloat162float(x); }
DEV __hip_bfloat16 f2bf(float x) { return __float2bfloat16(x); }
DEV float bfu2f(unsigned short u) {
    union { u32 i; float f; } c; c.i = ((u32)u) << 16; return c.f;
}
DEV unsigned short f2bfu(float x) {
    __hip_bfloat16 h = __float2bfloat16(x);
    return *reinterpret_cast<unsigned short*>(&h);
}
DEV float softplusf(float v) { return v > 20.f ? v : log1pf(__expf(v)); }
DEV float siluf(float v) { return v / (1.f + __expf(-v)); }
// fast softplus: ln(1+e^v) via v_exp_f32/v_log_f32 (log2-based).
DEV float softplus_fast(float v) {
    if (v > 20.f) return v;
    const float e = __builtin_amdgcn_exp2f(v * 1.44269504f);
    return 0.69314718f * __builtin_amdgcn_logf(1.f + e);
}

DEV void storeOut(float* C, size_t off, float v) { C[off] = v; }
DEV void storeOut(__hip_bfloat16* C, size_t off, float v) { C[off] = f2bf(v); }

// async 16B global -> LDS (global_load_lds_dwordx4).
// LDS destination must be wave-uniform base + lane*16 (HW constraint).
DEV void async16(void* lds, const void* g) {
    __builtin_amdgcn_global_load_lds(
        (const __attribute__((address_space(1))) u32*)(unsigned long long)g,
        (__attribute__((address_space(3))) u32*)(u32)(unsigned long long)lds,
        16, 0, 0);
}

// DPP-based add of lane (permuted) value; reduction over 16-lane rows.
// MUST stay as the builtin: compiler inserts required DPP hazard nops.
template <int CTRL>
DEV float dppadd(float v) {
    int x = __builtin_amdgcn_update_dpp(
        0, __builtin_bit_cast(int, v), CTRL, 0xF, 0xF, true);
    return v + __builtin_bit_cast(float, x);
}

// vectorized 8-elem fp32->bf16 cast at element index i*8
DEV void cast8(const float* __restrict__ in, __hip_bfloat16* __restrict__ out,
               size_t i8) {
    const size_t i = i8 * 8;
    const float4 a = *reinterpret_cast<const float4*>(in + i);
    const float4 b = *reinterpret_cast<const float4*>(in + i + 4);
    unsigned short r[8];
    r[0] = f2bfu(a.x); r[1] = f2bfu(a.y); r[2] = f2bfu(a.z); r[3] = f2bfu(a.w);
    r[4] = f2bfu(b.x); r[5] = f2bfu(b.y); r[6] = f2bfu(b.z); r[7] = f2bfu(b.w);
    *reinterpret_cast<uint4*>(out + i) = *reinterpret_cast<uint4*>(r);
}

// ---------------------------------------------------------------------------
// 256x256-tile deep-pipelined GEMM: C = A @ W^T + bias (bf16 in, bf16 out).
// 512 threads = 8 waves (2M x 4N), per-wave 128x64 output, BK=32.
// 4 LDS buffers, prefetch distance 3 tiles, counted vmcnt, T2 swizzle, T5.
// ---------------------------------------------------------------------------
__global__ __launch_bounds__(512, 2) void gemm256_bt(
    const __hip_bfloat16* __restrict__ A, int lda,
    const __hip_bfloat16* __restrict__ W, int ldw,
    const float* __restrict__ bias,
    __hip_bfloat16* __restrict__ C, int ldc, int K)
{
    __shared__ __align__(16) unsigned short As[4][256 * 32];  // 64 KB
    __shared__ __align__(16) unsigned short Bs[4][256 * 32];  // 64 KB

    const int t    = threadIdx.x;
    // T1: bijective XCD swizzle (nwg % 8 == 0 guaranteed by launch shapes)
    const int nwg  = gridDim.x * gridDim.y;
    const int orig = blockIdx.y * gridDim.x + blockIdx.x;
    const int swz  = (orig & 7) * (nwg >> 3) + (orig >> 3);
    const int mBase = (swz / gridDim.x) * 256;
    const int nBase = (swz % gridDim.x) * 256;

    const int wave = t >> 6;
    const int lane = t & 63;
    const int wm   = (wave >> 2) * 128;   // 2 M wave-groups
    const int wn   = (wave & 3) * 64;     // 4 N wave-groups
    const int ln15 = lane & 15;
    const int quad = lane >> 4;
    const int kof  = quad * 8;

    f32x4 acc[8][4];
    const f32x4 vzero = {0.f, 0.f, 0.f, 0.f};
#pragma unroll
    for (int i = 0; i < 8; ++i)
#pragma unroll
        for (int j = 0; j < 4; ++j) acc[i][j] = vzero;

    auto stage = [&](int buf, int k0, int half) {
        const int idx = half * 512 + t;                 // 0..1023 -> 16B slot
        const int le  = (idx * 8) ^ (((idx >> 3) & 3) << 3);
        const int r   = le >> 5;
        const int c   = le & 31;
        async16(&As[buf][idx * 8], A + (size_t)(mBase + r) * lda + k0 + c);
        async16(&Bs[buf][idx * 8], W + (size_t)(nBase + r) * ldw + k0 + c);
    };

    const int NT = K >> 5;

#pragma unroll 1
    for (int p = 0; p < 3 && p < NT; ++p) {
        stage(p, p << 5, 0);
        stage(p, p << 5, 1);
    }

#pragma unroll 1
    for (int T = 0; T < NT; ++T) {
        const int buf = T & 3;
        if (T + 2 < NT)      asm volatile("s_waitcnt vmcnt(8)" ::: "memory");
        else if (T + 1 < NT) asm volatile("s_waitcnt vmcnt(4)" ::: "memory");
        else                 asm volatile("s_waitcnt vmcnt(0)" ::: "memory");
        __builtin_amdgcn_s_barrier();          // all waves' vmcnt passed
        __builtin_amdgcn_sched_barrier(0);     // no ds_read hoists above

        const unsigned short* __restrict__ Ab = As[buf];
        const unsigned short* __restrict__ Bb = Bs[buf];
        const int k0n  = (T + 3) << 5;
        const int bufn = (T + 3) & 3;          // != buf; == (T-1)&3 (dead)

        // ---- phase 1: A-frags 0-3 + all B-frags, 16 MFMA ----
        bf16x8 af[4], bfr[4], af2[4];
#pragma unroll
        for (int i = 0; i < 4; ++i) {
            const int ra = wm + i * 16 + ln15;
            af[i] = *reinterpret_cast<const bf16x8*>(
                &Ab[(ra * 32 + kof) ^ (((ra >> 1) & 3) << 3)]);
            const int rb = wn + i * 16 + ln15;
            bfr[i] = *reinterpret_cast<const bf16x8*>(
                &Bb[(rb * 32 + kof) ^ (((rb >> 1) & 3) << 3)]);
        }
        if (T + 3 < NT) stage(bufn, k0n, 0);
        __builtin_amdgcn_s_barrier();
        __builtin_amdgcn_s_setprio(1);
#pragma unroll
        for (int i = 0; i < 4; ++i)
#pragma unroll
            for (int j = 0; j < 4; ++j)
                acc[i][j] = __builtin_amdgcn_mfma_f32_16x16x32_bf16(
                    af[i], bfr[j], acc[i][j], 0, 0, 0);
        __builtin_amdgcn_s_setprio(0);
        __builtin_amdgcn_sched_barrier(0);

        // ---- phase 2: A-frags 4-7 (reuse B-frags), 16 MFMA ----
#pragma unroll
        for (int i = 0; i < 4; ++i) {
            const int ra = wm + 64 + i * 16 + ln15;
            af2[i] = *reinterpret_cast<const bf16x8*>(
                &Ab[(ra * 32 + kof) ^ (((ra >> 1) & 3) << 3)]);
        }
        if (T + 3 < NT) stage(bufn, k0n, 1);
        __builtin_amdgcn_s_barrier();
        __builtin_amdgcn_s_setprio(1);
#pragma unroll
        for (int i = 0; i < 4; ++i)
#pragma unroll
            for (int j = 0; j < 4; ++j)
                acc[4 + i][j] = __builtin_amdgcn_mfma_f32_16x16x32_bf16(
                    af2[i], bfr[j], acc[4 + i][j], 0, 0, 0);
        __builtin_amdgcn_s_setprio(0);
        __builtin_amdgcn_sched_barrier(0);
    }

    // epilogue: C/D layout col = lane&15, row = quad*4 + reg
#pragma unroll
    for (int i = 0; i < 8; ++i) {
        const int gm = mBase + wm + i * 16 + quad * 4;
#pragma unroll
        for (int j = 0; j < 4; ++j) {
            const int gn = nBase + wn + j * 16 + ln15;
            const float bv = bias ? bias[gn] : 0.f;
#pragma unroll
            for (int r = 0; r < 4; ++r)
                C[(size_t)(gm + r) * ldc + gn] = f2bf(acc[i][j][r] + bv);
        }
    }
}

// ---------------------------------------------------------------------------
// C = A @ W^T + bias GEMM, bf16 inputs, DOUBLE-BUFFERED async LDS staging.
// Block tile 128x128, BK=64, 256 threads = 4 waves 2x2, wave does 64x64.
// T1 XCD swizzle (requires grid nwg % 8 == 0).
// ---------------------------------------------------------------------------
template <int ACT, typename OutT>
__global__ __launch_bounds__(256) void gemm_bt(
    const __hip_bfloat16* __restrict__ A, int lda,
    const __hip_bfloat16* __restrict__ W, int ldw,
    const float* __restrict__ bias,
    OutT* __restrict__ C, int ldc, int K)
{
    __shared__ __align__(16) unsigned short AsU[2][128 * 64];
    __shared__ __align__(16) unsigned short BsU[2][128 * 64];

    const int t     = threadIdx.x;
    const int nwg   = gridDim.x * gridDim.y;
    const int orig  = blockIdx.y * gridDim.x + blockIdx.x;
    const int swz   = (orig & 7) * (nwg >> 3) + (orig >> 3);
    const int mBase = (swz / gridDim.x) * 128;
    const int nBase = (swz % gridDim.x) * 128;
    const int wave  = t >> 6;
    const int lane  = t & 63;
    const int wm    = (wave >> 1) * 64;
    const int wn    = (wave & 1) * 64;
    const int ln15  = lane & 15;
    const int quad  = lane >> 4;

    f32x4 acc[4][4];
    const f32x4 vzero = {0.f, 0.f, 0.f, 0.f};
#pragma unroll
    for (int i = 0; i < 4; ++i)
#pragma unroll
        for (int j = 0; j < 4; ++j) acc[i][j] = vzero;

    auto stage = [&](int buf, int k0) {
#pragma unroll
        for (int i = 0; i < 4; ++i) {
            int idx = i * 256 + t;
            int r = idx >> 3;
            int c = (idx & 7) << 3;
            async16(&AsU[buf][idx * 8], A + (size_t)(mBase + r) * lda + k0 + c);
            async16(&BsU[buf][idx * 8], W + (size_t)(nBase + r) * ldw + k0 + c);
        }
    };

    const int nIter = K >> 6;
    stage(0, 0);

    for (int it = 0; it < nIter; ++it) {
        __syncthreads();   // buf[it&1] resident; prior reads of other buf done
        if (it + 1 < nIter) stage((it + 1) & 1, (it + 1) << 6);
        const unsigned short* As = AsU[it & 1];
        const unsigned short* Bs = BsU[it & 1];

#pragma unroll
        for (int kk = 0; kk < 64; kk += 32) {
            const int kof = kk + quad * 8;
            bf16x8 af[4], bfr[4];
#pragma unroll
            for (int i = 0; i < 4; ++i) {
                af[i]  = *reinterpret_cast<const bf16x8*>(&As[(wm + i * 16 + ln15) * 64 + kof]);
                bfr[i] = *reinterpret_cast<const bf16x8*>(&Bs[(wn + i * 16 + ln15) * 64 + kof]);
            }
#pragma unroll
            for (int i = 0; i < 4; ++i)
#pragma unroll
                for (int j = 0; j < 4; ++j)
                    acc[i][j] = __builtin_amdgcn_mfma_f32_16x16x32_bf16(af[i], bfr[j], acc[i][j], 0, 0, 0);
        }
    }

    // epilogue: C/D layout col = lane&15, row = quad*4 + reg
#pragma unroll
    for (int i = 0; i < 4; ++i) {
        const int gm = mBase + wm + i * 16 + quad * 4;
#pragma unroll
        for (int j = 0; j < 4; ++j) {
            const int gn = nBase + wn + j * 16 + ln15;
            const float bv = bias ? bias[gn] : 0.f;
#pragma unroll
            for (int r = 0; r < 4; ++r) {
                float v = acc[i][j][r] + bv;
                if (ACT == 1) v = softplusf(v);
                storeOut(C, (size_t)(gm + r) * ldc + gn, v);
            }
        }
    }
}

// ---------------------------------------------------------------------------
// Split-K variant: grid (nx, ny, SLICES); slice z handles K-range
// [z*K/SLICES, (z+1)*K/SLICES), stores fp32 partial at part + z*sliceElems.
// ---------------------------------------------------------------------------
__global__ __launch_bounds__(256) void gemm_bt_sk(
    const __hip_bfloat16* __restrict__ A, int lda,
    const __hip_bfloat16* __restrict__ W, int ldw,
    float* __restrict__ part, int ldc, int K, int slices, int sliceElems)
{
    __shared__ __align__(16) unsigned short AsU[2][128 * 64];
    __shared__ __align__(16) unsigned short BsU[2][128 * 64];

    const int t     = threadIdx.x;
    const int mBase = blockIdx.y * 128;
    const int nBase = blockIdx.x * 128;
    const int kLen  = K / slices;
    const int kOff  = blockIdx.z * kLen;
    const int wave  = t >> 6;
    const int lane  = t & 63;
    const int wm    = (wave >> 1) * 64;
    const int wn    = (wave & 1) * 64;
    const int ln15  = lane & 15;
    const int quad  = lane >> 4;

    f32x4 acc[4][4];
    const f32x4 vzero = {0.f, 0.f, 0.f, 0.f};
#pragma unroll
    for (int i = 0; i < 4; ++i)
#pragma unroll
        for (int j = 0; j < 4; ++j) acc[i][j] = vzero;

    auto stage = [&](int buf, int k0) {
#pragma unroll
        for (int i = 0; i < 4; ++i) {
            int idx = i * 256 + t;
            int r = idx >> 3;
            int c = (idx & 7) << 3;
            async16(&AsU[buf][idx * 8], A + (size_t)(mBase + r) * lda + k0 + c);
            async16(&BsU[buf][idx * 8], W + (size_t)(nBase + r) * ldw + k0 + c);
        }
    };

    const int nIter = kLen >> 6;
    stage(0, kOff);

    for (int it = 0; it < nIter; ++it) {
        __syncthreads();
        if (it + 1 < nIter) stage((it + 1) & 1, kOff + ((it + 1) << 6));
        const unsigned short* As = AsU[it & 1];
        const unsigned short* Bs = BsU[it & 1];

#pragma unroll
        for (int kk = 0; kk < 64; kk += 32) {
            const int kof = kk + quad * 8;
            bf16x8 af[4], bfr[4];
#pragma unroll
            for (int i = 0; i < 4; ++i) {
                af[i]  = *reinterpret_cast<const bf16x8*>(&As[(wm + i * 16 + ln15) * 64 + kof]);
                bfr[i] = *reinterpret_cast<const bf16x8*>(&Bs[(wn + i * 16 + ln15) * 64 + kof]);
            }
#pragma unroll
            for (int i = 0; i < 4; ++i)
#pragma unroll
                for (int j = 0; j < 4; ++j)
                    acc[i][j] = __builtin_amdgcn_mfma_f32_16x16x32_bf16(af[i], bfr[j], acc[i][j], 0, 0, 0);
        }
    }

    float* Cp = part + (size_t)blockIdx.z * sliceElems;
#pragma unroll
    for (int i = 0; i < 4; ++i) {
        const int gm = mBase + wm + i * 16 + quad * 4;
#pragma unroll
        for (int j = 0; j < 4; ++j) {
            const int gn = nBase + wn + j * 16 + ln15;
#pragma unroll
            for (int r = 0; r < 4; ++r)
                Cp[(size_t)(gm + r) * ldc + gn] = acc[i][j][r];
        }
    }
}

// sum 8 fp32 partials -> bf16 proj.  total = 2048*256 elems.
__global__ __launch_bounds__(256) void reduce_proj(
    const float* __restrict__ part, __hip_bfloat16* __restrict__ proj)
{
    int i = blockIdx.x * 256 + threadIdx.x;
    float s = 0.f;
#pragma unroll
    for (int z = 0; z < 8; ++z) s += part[(size_t)z * 524288 + i];
    proj[i] = f2bf(s);
}

// ---------------------------------------------------------------------------
// fp32 -> bf16 cast, 8 elems/thread (used for w_out after proj partials die).
// ---------------------------------------------------------------------------
__global__ __launch_bounds__(256) void cast_f32_bf16(
    const float* __restrict__ in, __hip_bfloat16* __restrict__ out)
{
    cast8(in, out, (size_t)blockIdx.x * 256 + threadIdx.x);
}

// ---------------------------------------------------------------------------
// FUSED prep: blocks [0,2048) cast u; [2048,10240) cast w_in;
// [10240,14336) build wcat; [14336,14592) cast w_dt.  One dispatch.
// ---------------------------------------------------------------------------
__global__ __launch_bounds__(256) void prep_all(
    const float* __restrict__ u, const float* __restrict__ w_in,
    const float* __restrict__ w_xdt, const float* __restrict__ w_xb,
    const float* __restrict__ w_xc, const float* __restrict__ w_dt,
    __hip_bfloat16* __restrict__ u_bf, __hip_bfloat16* __restrict__ w_in_bf,
    __hip_bfloat16* __restrict__ wcat, __hip_bfloat16* __restrict__ w_dt_bf)
{
    const int blk = blockIdx.x;
    const int t   = threadIdx.x;
    if (blk < 2048) {
        cast8(u, u_bf, (size_t)blk * 256 + t);
    } else if (blk < 10240) {
        cast8(w_in, w_in_bf, (size_t)(blk - 2048) * 256 + t);
    } else if (blk < 14336) {
        const int tid = (blk - 10240) * 256 + t;
        const int r = tid >> 12;
        const int c = tid & 4095;
        float v = 0.f;
        if (r < 128)      v = w_xdt[r * 4096 + c];
        else if (r < 144) v = w_xb[(r - 128) * 4096 + c];
        else if (r < 160) v = w_xc[(r - 144) * 4096 + c];
        wcat[tid] = f2bf(v);
    } else {
        cast8(w_dt, w_dt_bf, (size_t)(blk - 14336) * 256 + t);
    }
}

// ---------------------------------------------------------------------------
// Vectorized causal depthwise conv (win 4, left pad 3) + bias + silu over
// xz[:, :4096] -> xc, AND silu over xz[:, 4096:] IN PLACE (z-gate precompute
// for the scan).  8 outputs per thread, uint4 loads/stores.
// ---------------------------------------------------------------------------
__global__ __launch_bounds__(256) void conv_siluz(
    const __hip_bfloat16* __restrict__ xzr,
    __hip_bfloat16* __restrict__ xzw,          // same buffer, z-half writes
    const float* __restrict__ conv_w,
    const float* __restrict__ conv_b,
    __hip_bfloat16* __restrict__ xc)
{
    const int tid = blockIdx.x * 256 + threadIdx.x;
    if (tid < (1 << 20)) {
        const int row = tid >> 9;            // 0..2047 (b*1024 + l)
        const int d8  = (tid & 511) << 3;    // 0..4088 step 8
        const int l   = row & 1023;
        uint4 tv[4];
#pragma unroll
        for (int k = 0; k < 4; ++k) {
            const int ll = l - 3 + k;
            if (ll >= 0)
                tv[k] = *reinterpret_cast<const uint4*>(
                    &xzr[(size_t)(row - 3 + k) * 8192 + d8]);
            else
                tv[k] = make_uint4(0u, 0u, 0u, 0u);   // bf16 zeros
        }
        const float4 b0 = *reinterpret_cast<const float4*>(&conv_b[d8]);
        const float4 b1 = *reinterpret_cast<const float4*>(&conv_b[d8 + 4]);
        const unsigned short* t0 = (const unsigned short*)&tv[0];
        const unsigned short* t1 = (const unsigned short*)&tv[1];
        const unsigned short* t2 = (const unsigned short*)&tv[2];
        const unsigned short* t3 = (const unsigned short*)&tv[3];
        unsigned short o[8];
#pragma unroll
        for (int j = 0; j < 8; ++j) {
            const float4 w = *reinterpret_cast<const float4*>(&conv_w[(d8 + j) * 4]);
            float acc = (j < 4) ? ((const float*)&b0)[j] : ((const float*)&b1)[j - 4];
            acc += bfu2f(t0[j]) * w.x;
            acc += bfu2f(t1[j]) * w.y;
            acc += bfu2f(t2[j]) * w.z;
            acc += bfu2f(t3[j]) * w.w;
            o[j] = f2bfu(siluf(acc));
        }
        *reinterpret_cast<uint4*>(&xc[(size_t)row * 4096 + d8]) =
            *reinterpret_cast<const uint4*>(o);
    } else {
        const int zi  = tid - (1 << 20);
        const int row = zi >> 9;
        const int d8  = (zi & 511) << 3;
        const size_t a = (size_t)row * 8192 + 4096 + d8;
        const uint4 v = *reinterpret_cast<const uint4*>(&xzr[a]);
        const unsigned short* zv = (const unsigned short*)&v;
        unsigned short o[8];
#pragma unroll
        for (int j = 0; j < 8; ++j)
            o[j] = f2bfu(siluf(bfu2f(zv[j])));
        *reinterpret_cast<uint4*>(&xzw[a]) = *reinterpret_cast<const uint4*>(o);
    }
}

// ---------------------------------------------------------------------------
// selective scan with FUSED dt computation, 16 lanes/channel.
// 16 channels/block, 512 blocks, 256 threads.  LDS 42.2 KB.
// dt MFMA fragments load DIRECTLY from global (proj is L2-resident, zero
// intra-block reuse); w_dt fragments preloaded once into registers.
// 3-level DPP reduce + (n&7)==j capture; halves combined via shfl_xor in the
// defer-y tail.  z-half of xz holds PRE-GATED silu(z).
// ---------------------------------------------------------------------------
#define SCAN_T 128
#define ST4 132
#define ST2 136

__global__ __launch_bounds__(256) void scan_kernel(
    const __hip_bfloat16* __restrict__ proj,   // [2048,256]; dt-K at 0, B at 128, C at 144
    __hip_bfloat16* xcyg,                      // [2048, 4096] bf16 in/out
    const __hip_bfloat16* __restrict__ xz,     // [2048, 8192]; zg at 4096+d
    const __hip_bfloat16* __restrict__ wdt,    // [4096, 128] bf16
    const float* __restrict__ bdt,             // [4096] fp32
    const float* __restrict__ A_log,           // [4096, 16] fp32
    const float* __restrict__ Dp)              // [4096] fp32
{
    __shared__ __align__(16) float          s_dt[16 * ST4];   // [d][time]
    __shared__ __align__(16) float          s_xf[16 * ST4];   // [d][time] f32
    __shared__ __align__(16) float          s_Bf[16 * ST4];   // [state][time] f32
    __shared__ __align__(16) float          s_Cf[16 * ST4];   // [state][time] f32
    __shared__ __align__(16) unsigned short s_z [16 * ST2];   // [d][time] bf16
    __shared__ __align__(16) unsigned short s_y [16 * ST2];

    const int t    = threadIdx.x;
    const int g    = t >> 4;         // channel in block, 0..15
    const int n    = t & 15;         // state
    const int wave = t >> 6;
    const int lane = t & 63;
    const int ln15 = lane & 15;
    const int quad = lane >> 4;
    const int wm32 = wave * 32;      // wave's 32-row t-stripe of the dt tile
    const int ch0  = blockIdx.x * 16;
    const int b    = ch0 >> 12;
    const int d0   = ch0 & 4095;
    const int d    = d0 + g;

    const float A2   = -__expf(A_log[d * 16 + n]) * 1.44269504f;
    const float Dpar = Dp[d];
    const size_t rowBase = (size_t)b * 1024;
    const float bdtv = bdt[d0 + ln15];   // lane's d-column of the dt tile

    // preload w_dt fragments once (chunk-invariant): row = d0+ln15,
    // cols ks*32 + quad*8 .. +7
    bf16x8 wfrag[4];
#pragma unroll
    for (int ks = 0; ks < 4; ++ks)
        wfrag[ks] = *reinterpret_cast<const bf16x8*>(
            &wdt[(size_t)(d0 + ln15) * 128 + ks * 32 + quad * 8]);

    // staging thread mappings (128 time-rows per chunk)
    const int lrow = t >> 1;             // 0..127
    const int lh8  = (t & 1) << 3;       // 0 or 8

    uint4 rx, rz, rBv, rCv;
    auto load_chunk = [&](int t0) {
        rx  = *reinterpret_cast<const uint4*>(
            &xcyg[(rowBase + t0 + lrow) * 4096 + d0 + lh8]);
        rz  = *reinterpret_cast<const uint4*>(
            &xz[(rowBase + t0 + lrow) * 8192 + 4096 + d0 + lh8]);
        rBv = *reinterpret_cast<const uint4*>(
            &proj[(rowBase + t0 + lrow) * 256 + 128 + lh8]);
        rCv = *reinterpret_cast<const uint4*>(
            &proj[(rowBase + t0 + lrow) * 256 + 144 + lh8]);
    };

    load_chunk(0);
    float h = 0.f;

#pragma unroll 1
    for (int c = 0; c < 1024 / SCAN_T; ++c) {
        const int t0 = c * SCAN_T;
        __syncthreads();                 // prior chunk's LDS reads complete

        // issue proj-chunk MFMA fragment loads early (global->VGPR; L2-hot).
        // rows wm32..wm32+31 of the [128t x 128k] dt-K panel, per-lane 16B.
        bf16x8 paf[2][4];
#pragma unroll
        for (int ks = 0; ks < 4; ++ks)
#pragma unroll
            for (int i = 0; i < 2; ++i)
                paf[i][ks] = *reinterpret_cast<const bf16x8*>(
                    &proj[(rowBase + t0 + wm32 + i * 16 + ln15) * 256 +
                          ks * 32 + quad * 8]);

        // write prefetched x/z/B/C regs into LDS (transposed; x/B/C -> f32)
        {
            const unsigned short* px = (const unsigned short*)&rx;
            const unsigned short* pz = (const unsigned short*)&rz;
            const unsigned short* pB = (const unsigned short*)&rBv;
            const unsigned short* pC = (const unsigned short*)&rCv;
#pragma unroll
            for (int jj = 0; jj < 8; ++jj) {
                s_xf[(lh8 + jj) * ST4 + lrow] = bfu2f(px[jj]);
                s_z [(lh8 + jj) * ST2 + lrow] = pz[jj];
                s_Bf[(lh8 + jj) * ST4 + lrow] = bfu2f(pB[jj]);
                s_Cf[(lh8 + jj) * ST4 + lrow] = bfu2f(pC[jj]);
            }
        }
        __syncthreads();
        if (c + 1 < 1024 / SCAN_T) load_chunk(t0 + SCAN_T);

        // ---- fused dt tile: [128 t x 16 d] = softplus(projK @ wdt^T + bdt)
        {
            f32x4 dacc[2];
            const f32x4 vz4 = {0.f, 0.f, 0.f, 0.f};
            dacc[0] = vz4; dacc[1] = vz4;
#pragma unroll
            for (int ks = 0; ks < 4; ++ks)
#pragma unroll
                for (int i = 0; i < 2; ++i)
                    dacc[i] = __builtin_amdgcn_mfma_f32_16x16x32_bf16(
                        paf[i][ks], wfrag[ks], dacc[i], 0, 0, 0);
            // epilogue: C[m=t, n=d]; col=ln15, row=quad*4+r -> s_dt[d][t]
#pragma unroll
            for (int i = 0; i < 2; ++i) {
                const int tb = wm32 + i * 16 + quad * 4;
                const int dd = ln15;
                f32x4 w;
#pragma unroll
                for (int r = 0; r < 4; ++r)
                    w[r] = softplus_fast(dacc[i][r] + bdtv);
                *reinterpret_cast<f32x4*>(&s_dt[dd * ST4 + tb]) = w;
            }
        }
        __syncthreads();                 // s_dt visible to all waves

#pragma unroll 1
        for (int l0 = 0; l0 < SCAN_T; l0 += 8) {
            const float4 vd0 = *reinterpret_cast<const float4*>(&s_dt[g * ST4 + l0]);
            const float4 vd1 = *reinterpret_cast<const float4*>(&s_dt[g * ST4 + l0 + 4]);
            const float4 vx0 = *reinterpret_cast<const float4*>(&s_xf[g * ST4 + l0]);
            const float4 vx1 = *reinterpret_cast<const float4*>(&s_xf[g * ST4 + l0 + 4]);
            const float4 vB0 = *reinterpret_cast<const float4*>(&s_Bf[n * ST4 + l0]);
            const float4 vB1 = *reinterpret_cast<const float4*>(&s_Bf[n * ST4 + l0 + 4]);
            const float4 vC0 = *reinterpret_cast<const float4*>(&s_Cf[n * ST4 + l0]);
            const float4 vC1 = *reinterpret_cast<const float4*>(&s_Cf[n * ST4 + l0 + 4]);
            const float* fd0 = (const float*)&vd0;
            const float* fd1 = (const float*)&vd1;
            const float* fx0 = (const float*)&vx0;
            const float* fx1 = (const float*)&vx1;
            const float* fB0 = (const float*)&vB0;
            const float* fB1 = (const float*)&vB1;
            const float* fC0 = (const float*)&vC0;
            const float* fC1 = (const float*)&vC1;
            float psum = 0.f;
#pragma unroll
            for (int j = 0; j < 8; ++j) {
                const float dtv = (j < 4) ? fd0[j] : fd1[j - 4];
                const float xv  = (j < 4) ? fx0[j] : fx1[j - 4];
                const float Bn  = (j < 4) ? fB0[j] : fB1[j - 4];
                const float Cn  = (j < 4) ? fC0[j] : fC1[j - 4];
                const float e   = __builtin_amdgcn_exp2f(dtv * A2);
                h = fmaf(h, e, (xv * dtv) * Bn);
                float p = h * Cn;
                p = dppadd<0xB1>(p);    // quad xor1
                p = dppadd<0x4E>(p);    // quad xor2
                p = dppadd<0x141>(p);   // half-row mirror: 8-lane sums
                psum = ((n & 7) == j) ? p : psum;   // capture half-sum
            }
            // combine 8-lane halves (lane n <-> n^8), then defer-y tail:
            // lanes 0-7 each emit y for one step.
            const float pother = __shfl_xor(psum, 8);
            if (n < 8) {
                const float xvn = s_xf[g * ST4 + l0 + n];
                const float zgv = bfu2f(s_z[g * ST2 + l0 + n]);
                s_y[g * ST2 + l0 + n] =
                    f2bfu((psum + pother + Dpar * xvn) * zgv);
            }
        }
        __syncthreads();

        {
            unsigned short tmp[8];
#pragma unroll
            for (int jj = 0; jj < 8; ++jj) tmp[jj] = s_y[(lh8 + jj) * ST2 + lrow];
            *reinterpret_cast<uint4*>(
                &xcyg[(rowBase + t0 + lrow) * 4096 + d0 + lh8]) =
                *reinterpret_cast<const uint4*>(tmp);
        }
    }
}

// ---------------------------------------------------------------------------
extern "C" void kernel_launch(void* const* d_in, const int* in_sizes, int n_in,
                              void* d_out, int out_size, void* d_ws, size_t ws_size,
                              hipStream_t stream)
{
    const float* u      = (const float*)d_in[0];
    const float* w_in   = (const float*)d_in[1];
    const float* b_in   = (const float*)d_in[2];
    const float* w_out  = (const float*)d_in[3];
    const float* b_out  = (const float*)d_in[4];
    const float* w_dt   = (const float*)d_in[5];
    const float* b_dt   = (const float*)d_in[6];
    const float* w_xdt  = (const float*)d_in[7];
    const float* w_xb   = (const float*)d_in[8];
    const float* w_xc   = (const float*)d_in[9];
    const float* conv_w = (const float*)d_in[10];
    const float* conv_b = (const float*)d_in[11];
    const float* A_log  = (const float*)d_in[12];
    const float* D_par  = (const float*)d_in[13];
    float* out = (float*)d_out;

    char* ws = (char*)d_ws;
    __hip_bfloat16* xz    = (__hip_bfloat16*)(ws);             // [2048,8192] 33.5 MB
    __hip_bfloat16* xc    = (__hip_bfloat16*)(ws + 33554432);  // [2048,4096] 16.8 MB
    __hip_bfloat16* u_bf  = (__hip_bfloat16*)(ws + 33554432);  // dead before xc written
    __hip_bfloat16* wcat  = (__hip_bfloat16*)(ws + 50331648);  // [256,4096]  2.1 MB
    __hip_bfloat16* w_dt_bf = (__hip_bfloat16*)(ws + 52428800);// [4096,128]  1.0 MB
    __hip_bfloat16* w_in_bf  = (__hip_bfloat16*)(ws + 53477376); // [8192,2048] bf16 33.5MB
    float*          projPart = (float*)(ws + 53477376);         // [8,2048,256] 16.8 MB (after w_in_bf dead)
    __hip_bfloat16* w_out_bf = (__hip_bfloat16*)(ws + 53477376); // after projPart dead
    __hip_bfloat16* proj  = (__hip_bfloat16*)(ws + 87031808);   // [2048,256] 1.0 MB
    // Layout audit (live ranges):
    //   [0,        33554432)  xz            (step2 .. scan)
    //   [33554432, 50331648)  u_bf -> xc    (u_bf dead after step2; xc from step3)
    //   [50331648, 52428800)  wcat          (prep .. step4)
    //   [52428800, 53477376)  w_dt_bf       (prep .. scan)
    //   [53477376, 87031808)  w_in_bf / projPart / w_out_bf (sequential reuse)
    //   [87031808, 88080384)  proj          (reduce_proj .. scan)
    // total 88.1 MB

    // 0+1. fused prep: cast u, cast w_in, build wcat, cast w_dt (1 dispatch)
    prep_all<<<14592, 256, 0, stream>>>(
        u, w_in, w_xdt, w_xb, w_xc, w_dt, u_bf, w_in_bf, wcat, w_dt_bf);

    // 2. in_proj: xz = u @ w_in^T + b_in   (M=2048, N=8192, K=2048)
    gemm256_bt<<<dim3(32, 8), 512, 0, stream>>>(
        u_bf, 2048, w_in_bf, 2048, b_in, xz, 8192, 2048);

    // 3. conv + silu -> xc; silu(z) in place over xz z-half (z-gate)
    conv_siluz<<<8192, 256, 0, stream>>>(xz, xz, conv_w, conv_b, xc);

    // 4. proj = xc @ wcat^T, split-K=8      (M=2048, N=256, K=4096)
    gemm_bt_sk<<<dim3(2, 16, 8), 256, 0, stream>>>(
        xc, 4096, wcat, 4096, projPart, 256, 4096, 8, 524288);
    reduce_proj<<<2048, 256, 0, stream>>>(projPart, proj);

    // 5. cast w_out into projPart region (dead after reduce_proj)
    cast_f32_bf16<<<4096, 256, 0, stream>>>(w_out, w_out_bf);

    // 6+7. selective scan with FUSED dt GEMM -> yg (in-place over xc)
    scan_kernel<<<512, 256, 0, stream>>>(
        proj, xc, xz, w_dt_bf, b_dt, A_log, D_par);

    // 8. out = yg @ w_out^T + b_out          (M=2048, N=2048, K=4096)
    gemm_bt<0, float><<<dim3(16, 16), 256, 0, stream>>>(
        xc, 4096, w_out_bf, 4096, b_out, out, 2048, 4096);
}